// Round 9
// baseline (262.768 us; speedup 1.0000x reference)
//
#include <hip/hip_runtime.h>
#include <hip/hip_bf16.h>
#include <stdint.h>
#include <stddef.h>

typedef __bf16 bf16;
typedef __bf16 bf16x8 __attribute__((ext_vector_type(8)));
typedef float f32x4 __attribute__((ext_vector_type(4)));

#define BATCH 4096
#define KIH 7808          // Wih K
#define KTOT 7936         // 62 slots * 128 (h0 appended)
#define NG 512            // 4*LH gates
#define LH 128
#define HD 64
#define ED 128
#define SPLITK 4

// workspace layout (byte offsets)
#define OFF_WCAT 0u                 //  8,126,464  bf16 Wcat[512][7936]
#define OFF_GPART 8126464u          // 33,554,432  f32 gpart[4][4096][512]
#define OFF_XT   41680896u          //  2,097,152  bf16 xtail[4096][256]
#define OFF_AB   43778048u          //     76,800  bf16 ab8[300][128]
#define OFF_MV   43854848u          //    230,400  bf16 mv8[900][128]
#define OFF_ADDR 44085248u          //  2,097,152  u32 addrs[4096][64]
// end: 46,182,400 B

// out layout: probs[B*9] | h1[B*128] | c1[B*128]
#define O_H1 (BATCH * 9)
#define O_C1 (BATCH * 9 + BATCH * LH)

// ---------------------------------------------------------------------------
// Kernel 1: fused prep.  blocks 0..4095: build_pre (per-row offsets + xtail)
//                        blocks 4096..4607: convert_w
//                        blocks 4608..5207: convert_emb
// ---------------------------------------------------------------------------
__global__ void prep(const int* __restrict__ ab_ids,
                     const int* __restrict__ mv_ids,
                     const float* __restrict__ numerical,
                     const float* __restrict__ h0,
                     const float* __restrict__ numW,
                     const float* __restrict__ numb,
                     const float* __restrict__ Wih,
                     const float* __restrict__ Whh,
                     const float* __restrict__ ab_emb,
                     const float* __restrict__ mv_emb,
                     uint8_t* __restrict__ ws) {
    const int bid = blockIdx.x;
    const int t = threadIdx.x;  // 0..255

    if (bid < BATCH) {
        // ---- build_pre ----
        bf16* xtail = (bf16*)(ws + OFF_XT);
        uint32_t* addrs = (uint32_t*)(ws + OFF_ADDR);
        const int b = bid;

        __shared__ int ids[60];
        __shared__ float numr[84];
        if (t < 60) ids[t] = (t < 12) ? ab_ids[b * 12 + t] : mv_ids[b * 48 + (t - 12)];
        if (t >= 128 && t < 128 + 84) numr[t - 128] = numerical[(size_t)b * 84 + (t - 128)];
        __syncthreads();

        if (t < 128) {
            float acc = numb[t];
#pragma unroll 4
            for (int k = 0; k < 84; ++k)
                acc += numr[k] * numW[t * 84 + k];
            xtail[(size_t)b * 256 + t] = (bf16)acc;
        } else {
            const int tt = t - 128;
            xtail[(size_t)b * 256 + 128 + tt] = (bf16)h0[(size_t)b * LH + tt];
        }

        if (t < 64) {
            uint32_t off;
            if (t < 12) off = OFF_AB + (uint32_t)ids[t] * 256u;
            else if (t < 60) off = OFF_MV + (uint32_t)ids[t] * 256u;
            else if (t == 60) off = OFF_XT + (uint32_t)b * 512u;
            else if (t == 61) off = OFF_XT + (uint32_t)b * 512u + 256u;
            else off = OFF_XT;  // unused slots 62,63
            addrs[(size_t)b * 64 + t] = off;
        }
    } else if (bid < BATCH + 512) {
        // ---- convert_w ----
        bf16* Wcat = (bf16*)(ws + OFF_WCAT);
        const int n = bid - BATCH;
        const float* src_ih = Wih + (size_t)n * KIH;
        const float* src_hh = Whh + (size_t)n * LH;
        bf16* dst = Wcat + (size_t)n * KTOT;
        for (int k4 = t; k4 < KTOT / 4; k4 += 256) {
            const int k = k4 * 4;
            const float4 v = (k < KIH) ? *(const float4*)(src_ih + k)
                                       : *(const float4*)(src_hh + (k - KIH));
            bf16 o0 = (bf16)v.x, o1 = (bf16)v.y, o2 = (bf16)v.z, o3 = (bf16)v.w;
            dst[k] = o0; dst[k + 1] = o1; dst[k + 2] = o2; dst[k + 3] = o3;
        }
    } else {
        // ---- convert_emb ----
        bf16* ab8 = (bf16*)(ws + OFF_AB);
        bf16* mv8 = (bf16*)(ws + OFF_MV);
        const int i = (bid - BATCH - 512) * 256 + t;   // 0..153599
        if (i < 300 * 128) ab8[i] = (bf16)ab_emb[i];
        else if (i < 1200 * 128) mv8[i - 300 * 128] = (bf16)mv_emb[i - 300 * 128];
    }
}

// ---------------------------------------------------------------------------
// Kernel 2: gpart[bz] = x @ Wcat.T partial.  BARRIER-FREE K-LOOP:
// A and B fragments loaded straight from L2 (global 16-B vector loads) into
// registers with 1-iteration ping-pong prefetch. No LDS staging at all
// (LDS only holds the per-row gather offsets, read via broadcast ds_read).
// Block = 4 m-waves x 1 n-range(64) -> B gets 4x L1 reuse.
// Wave tile 64x64, 4x4 16x16x32 bf16 MFMA. Grid 16 x 8 x SPLITK.
// ---------------------------------------------------------------------------
__global__ __launch_bounds__(256, 2) void gemm_gates(
    const uint8_t* __restrict__ wsbase,
    const bf16* __restrict__ Wcat,
    const uint32_t* __restrict__ addrs,
    float* __restrict__ gpart) {
    __shared__ uint32_t adr[17][256];   // [slot-local][block row]

    const int tid = threadIdx.x;
    const int w = tid >> 6;       // wave 0..3 (m dimension)
    const int lane = tid & 63;
    const int bm = blockIdx.x;    // 0..15 (256 rows)
    const int bn = blockIdx.y;    // 0..7  (64 cols)
    const int bz = blockIdx.z;    // 0..3
    const int kt_beg = bz * 31;
    const int kt_end = kt_beg + 31;
    const int s0 = kt_beg >> 1;
    const int ns = ((kt_end - 1) >> 1) - s0 + 1;   // 16 or 17

    for (int i = tid; i < ns * 256; i += 256)
        adr[i >> 8][i & 255] =
            addrs[(size_t)(bm * 256 + (i & 255)) * 64 + s0 + (i >> 8)];
    __syncthreads();   // the only block-wide barrier

    const int nl = lane & 15;     // n/m fragment index
    const int kg = lane >> 4;     // k-group

    // B row base pointers (constant through the loop)
    const bf16* pB[4];
#pragma unroll
    for (int t = 0; t < 4; ++t)
        pB[t] = Wcat + (size_t)(bn * 64 + t * 16 + nl) * KTOT + kg * 8;

    f32x4 acc[4][4];
#pragma unroll
    for (int i = 0; i < 4; ++i)
#pragma unroll
        for (int j = 0; j < 4; ++j)
#pragma unroll
            for (int r = 0; r < 4; ++r) acc[i][j][r] = 0.f;

    uint32_t aofs[4];   // current slot's A row offsets for this lane's 4 frag rows

    auto refresh = [&](int kt) {   // load adr for slot of kt
        const int sl = (kt >> 1) - s0;
#pragma unroll
        for (int t = 0; t < 4; ++t)
            aofs[t] = adr[sl][w * 64 + t * 16 + nl];   // 4 lanes/addr: broadcast
    };

    auto loadbank = [&](int kt, bf16x8 (&af)[4][2], bf16x8 (&bfr)[4][2]) {
        const int hb = (kt & 1) * 128;       // byte offset within 256-B slot row
        const size_t bofs = (size_t)kt * 64; // element offset in Wcat row
#pragma unroll
        for (int t = 0; t < 4; ++t) {
            const uint8_t* pa = wsbase + aofs[t] + hb + kg * 16;
            af[t][0] = *(const bf16x8*)(pa);
            af[t][1] = *(const bf16x8*)(pa + 64);
            bfr[t][0] = *(const bf16x8*)(pB[t] + bofs);
            bfr[t][1] = *(const bf16x8*)(pB[t] + bofs + 32);
        }
    };

    auto compute = [&](bf16x8 (&af)[4][2], bf16x8 (&bfr)[4][2]) {
#pragma unroll
        for (int ks = 0; ks < 2; ++ks)
#pragma unroll
            for (int ti = 0; ti < 4; ++ti)
#pragma unroll
                for (int tj = 0; tj < 4; ++tj)
                    acc[ti][tj] = __builtin_amdgcn_mfma_f32_16x16x32_bf16(
                        af[ti][ks], bfr[tj][ks], acc[ti][tj], 0, 0, 0);
    };

    bf16x8 a0[4][2], b0[4][2], a1[4][2], b1[4][2];

    int kt = kt_beg;
    refresh(kt);
    loadbank(kt, a0, b0);
    // 15 pairs consume kt_beg .. kt_beg+29; bank0 ends holding kt_beg+30
#pragma unroll 1
    for (int it = 0; it < 15; ++it) {
        const int k1 = kt + 1;
        if ((k1 & 1) == 0) refresh(k1);
        loadbank(k1, a1, b1);
        compute(a0, b0);
        const int k2 = kt + 2;
        if ((k2 & 1) == 0) refresh(k2);
        loadbank(k2, a0, b0);
        compute(a1, b1);
        kt += 2;
    }
    compute(a0, b0);   // kt_beg + 30

    // ---- epilogue: plain stores to this bz's partial buffer ----
    float* gdst = gpart + (size_t)bz * BATCH * NG;
    const int mlo = kg * 4;
#pragma unroll
    for (int ti = 0; ti < 4; ++ti)
#pragma unroll
        for (int tj = 0; tj < 4; ++tj) {
            const int mg = bm * 256 + w * 64 + ti * 16 + mlo;
            const int ng = bn * 64 + tj * 16 + nl;
            float* dst = gdst + (size_t)mg * NG + ng;
#pragma unroll
            for (int r = 0; r < 4; ++r)
                dst[(size_t)r * NG] = acc[ti][tj][r];
        }
}

// ---------------------------------------------------------------------------
// Kernel 3: fused tail. 256 blocks x 128 threads (2 waves); 16 rows/block.
// Phase A: sum split-K partials + LSTM pointwise -> h1/c1 (fp32 out),
//          h1 bf16 into LDS.
// Phase B: MFMA MLP chain h1 -> u -> feat -> logits, softmax + masked renorm.
// ---------------------------------------------------------------------------
__global__ __launch_bounds__(128, 3) void tail(
    const float* __restrict__ gpart, const float* __restrict__ bih,
    const float* __restrict__ bhh, const float* __restrict__ c0,
    const float* __restrict__ mask,
    const float* __restrict__ W1, const float* __restrict__ b1,
    const float* __restrict__ W2, const float* __restrict__ b2,
    const float* __restrict__ Wa, const float* __restrict__ ba,
    float* __restrict__ out) {
    __shared__ bf16 W1f[8192];    // 16 frags (nt<4,kt<4)
    __shared__ bf16 W2f[8192];    // 16 frags (nt<8,kt<2)
    __shared__ bf16 Waf[2048];    // 4 frags (kt<4)
    __shared__ bf16 h1s[16 * 128];
    __shared__ bf16 uS[16 * 64];
    __shared__ bf16 fS[16 * 128];
    __shared__ float b1s[64];
    __shared__ float b2s[128];
    __shared__ float bas[16];

    const int tid = threadIdx.x;
    const int b0 = blockIdx.x * 16;

    // ---- stage weights as B-fragments: lane holds n=l&15, k=(l>>4)*8+j ----
    for (int e = tid; e < 8192; e += 128) {     // W1 (64x128)
        const int j = e & 7, ln = (e >> 3) & 63, fid = e >> 9;
        const int kt = fid & 3, nt = fid >> 2;
        const int n = nt * 16 + (ln & 15);
        const int k = kt * 32 + (ln >> 4) * 8 + j;
        W1f[e] = (bf16)W1[n * 128 + k];
    }
    for (int e = tid; e < 8192; e += 128) {     // W2 (128x64)
        const int j = e & 7, ln = (e >> 3) & 63, fid = e >> 9;
        const int kt = fid & 1, nt = fid >> 1;
        const int n = nt * 16 + (ln & 15);
        const int k = kt * 32 + (ln >> 4) * 8 + j;
        W2f[e] = (bf16)W2[n * 64 + k];
    }
    for (int e = tid; e < 2048; e += 128) {     // Wa (9x128, zero-padded)
        const int j = e & 7, ln = (e >> 3) & 63, kt = e >> 9;
        const int n = ln & 15;
        const int k = kt * 32 + (ln >> 4) * 8 + j;
        Waf[e] = (n < 9) ? (bf16)Wa[n * 128 + k] : (bf16)0.f;
    }
    if (tid < 64) b1s[tid] = b1[tid];
    if (tid < 16) bas[tid] = (tid < 9) ? ba[tid] : 0.f;
    if (tid < 128) b2s[tid] = b2[tid];

    // ---- phase A: gates -> h1/c1 for 16 rows ----
#pragma unroll
    for (int i = 0; i < 16; ++i) {
        const int p = tid + 128 * i;        // (row, unit) pair
        const int uu = p & 127;
        const int r = p >> 7;
        const int b = b0 + r;
        float gv[4];
#pragma unroll
        for (int q = 0; q < 4; ++q)
            gv[q] = bih[q * 128 + uu] + bhh[q * 128 + uu];
#pragma unroll
        for (int z = 0; z < SPLITK; ++z) {
            const float* gz = gpart + ((size_t)z * BATCH + b) * NG + uu;
#pragma unroll
            for (int q = 0; q < 4; ++q) gv[q] += gz[q * 128];
        }
        const float iv = 1.f / (1.f + __expf(-gv[0]));
        const float fv = 1.f / (1.f + __expf(-gv[1]));
        const float gg = tanhf(gv[2]);
        const float ov = 1.f / (1.f + __expf(-gv[3]));
        const float c1 = fv * c0[(size_t)b * LH + uu] + iv * gg;
        const float h1 = ov * tanhf(c1);
        out[O_H1 + (size_t)b * LH + uu] = h1;
        out[O_C1 + (size_t)b * LH + uu] = c1;
        h1s[r * 128 + uu] = (bf16)h1;
    }
    __syncthreads();

    const int wv = tid >> 6, lane = tid & 63;
    const int nl = lane & 15, kg = lane >> 4;

    // ---- A-frags of h1 tile (16x128) ----
    bf16x8 ah[4];
#pragma unroll
    for (int kt = 0; kt < 4; ++kt)
        ah[kt] = *(const bf16x8*)&h1s[nl * 128 + kt * 32 + kg * 8];

    // ---- stage 1: u = relu(h1 @ W1^T + b1) (16x64); waves split nt ----
#pragma unroll
    for (int t2 = 0; t2 < 2; ++t2) {
        const int nt = wv * 2 + t2;
        f32x4 a = {0.f, 0.f, 0.f, 0.f};
#pragma unroll
        for (int kt = 0; kt < 4; ++kt)
            a = __builtin_amdgcn_mfma_f32_16x16x32_bf16(
                ah[kt], *(const bf16x8*)&W1f[((nt * 4 + kt) * 64 + lane) * 8], a, 0, 0, 0);
        const int n = nt * 16 + nl;
#pragma unroll
        for (int r = 0; r < 4; ++r)
            uS[(kg * 4 + r) * 64 + n] = (bf16)fmaxf(a[r] + b1s[n], 0.f);
    }
    __syncthreads();

    bf16x8 au[2];
#pragma unroll
    for (int kt = 0; kt < 2; ++kt)
        au[kt] = *(const bf16x8*)&uS[nl * 64 + kt * 32 + kg * 8];

    // ---- stage 2: feat = u @ W2^T + b2 (16x128); waves split nt ----
#pragma unroll
    for (int t2 = 0; t2 < 4; ++t2) {
        const int nt = wv * 4 + t2;
        f32x4 a = {0.f, 0.f, 0.f, 0.f};
#pragma unroll
        for (int kt = 0; kt < 2; ++kt)
            a = __builtin_amdgcn_mfma_f32_16x16x32_bf16(
                au[kt], *(const bf16x8*)&W2f[((nt * 2 + kt) * 64 + lane) * 8], a, 0, 0, 0);
        const int n = nt * 16 + nl;
#pragma unroll
        for (int r = 0; r < 4; ++r)
            fS[(kg * 4 + r) * 128 + n] = (bf16)(a[r] + b2s[n]);
    }
    __syncthreads();

    // ---- stage 3 + softmax: wave 0 only ----
    if (wv == 0) {
        bf16x8 afr[4];
#pragma unroll
        for (int kt = 0; kt < 4; ++kt)
            afr[kt] = *(const bf16x8*)&fS[nl * 128 + kt * 32 + kg * 8];

        f32x4 lg4 = {0.f, 0.f, 0.f, 0.f};
#pragma unroll
        for (int kt = 0; kt < 4; ++kt)
            lg4 = __builtin_amdgcn_mfma_f32_16x16x32_bf16(
                afr[kt], *(const bf16x8*)&Waf[(kt * 64 + lane) * 8], lg4, 0, 0, 0);

#pragma unroll
        for (int r = 0; r < 4; ++r) {
            const int b = b0 + kg * 4 + r;
            float lg = (nl < 9) ? lg4[r] + bas[nl] : -1e30f;
            float mx = lg;
#pragma unroll
            for (int off = 1; off < 16; off <<= 1)
                mx = fmaxf(mx, __shfl_xor(mx, off, 64));
            const float e = (nl < 9) ? __expf(lg - mx) : 0.f;
            const float mv = (nl < 9) ? mask[(size_t)b * 9 + nl] : 0.f;
            float tot = e, ms = e * mv;
#pragma unroll
            for (int off = 1; off < 16; off <<= 1) {
                tot += __shfl_xor(tot, off, 64);
                ms += __shfl_xor(ms, off, 64);
            }
            if (nl < 9)
                out[(size_t)b * 9 + nl] = (ms > 0.f) ? e * mv / ms : e / tot;
        }
    }
}

// ---------------------------------------------------------------------------
extern "C" void kernel_launch(void* const* d_in, const int* in_sizes, int n_in,
                              void* d_out, int out_size, void* d_ws, size_t ws_size,
                              hipStream_t stream) {
    const int* ab_ids = (const int*)d_in[0];
    const int* mv_ids = (const int*)d_in[1];
    const float* numerical = (const float*)d_in[2];
    const float* mask = (const float*)d_in[3];
    const float* h0 = (const float*)d_in[4];
    const float* c0 = (const float*)d_in[5];
    const float* ab_emb = (const float*)d_in[6];
    const float* mv_emb = (const float*)d_in[7];
    const float* numW = (const float*)d_in[8];
    const float* numb = (const float*)d_in[9];
    const float* Wih = (const float*)d_in[10];
    const float* Whh = (const float*)d_in[11];
    const float* bih = (const float*)d_in[12];
    const float* bhh = (const float*)d_in[13];
    const float* W1 = (const float*)d_in[14];
    const float* b1 = (const float*)d_in[15];
    const float* W2 = (const float*)d_in[16];
    const float* b2 = (const float*)d_in[17];
    const float* Wa = (const float*)d_in[18];
    const float* ba = (const float*)d_in[19];
    float* out = (float*)d_out;

    uint8_t* ws = (uint8_t*)d_ws;
    bf16* Wcat = (bf16*)(ws + OFF_WCAT);
    float* gpart = (float*)(ws + OFF_GPART);
    uint32_t* addrs = (uint32_t*)(ws + OFF_ADDR);

    prep<<<BATCH + 512 + 600, 256, 0, stream>>>(
        ab_ids, mv_ids, numerical, h0, numW, numb, Wih, Whh, ab_emb, mv_emb, ws);
    gemm_gates<<<dim3(16, 8, SPLITK), 256, 0, stream>>>(ws, Wcat, addrs, gpart);
    tail<<<BATCH / 16, 128, 0, stream>>>(gpart, bih, bhh, c0, mask,
                                         W1, b1, W2, b2, Wa, ba, out);
}

// Round 10
// 199.258 us; speedup vs baseline: 1.3187x; 1.3187x over previous
//
#include <hip/hip_runtime.h>
#include <hip/hip_bf16.h>
#include <stdint.h>
#include <stddef.h>

typedef __bf16 bf16;
typedef __bf16 bf16x8 __attribute__((ext_vector_type(8)));
typedef float f32x4 __attribute__((ext_vector_type(4)));

#define BATCH 4096
#define KIH 7808          // Wih K
#define KTOT 7936         // 62 slots * 128 (h0 appended)
#define NG 512            // 4*LH gates
#define LH 128
#define HD 64
#define ED 128
#define SPLITK 4

// workspace layout (byte offsets)
#define OFF_WCAT 0u                 //  8,126,464  bf16 Wcat[512][7936]
#define OFF_GPART 8126464u          // 33,554,432  f32 gpart[4][4096][512]
#define OFF_XT   41680896u          //  2,097,152  bf16 xtail[4096][256]
#define OFF_AB   43778048u          //     76,800  bf16 ab8[300][128]
#define OFF_MV   43854848u          //    230,400  bf16 mv8[900][128]
#define OFF_ADDR 44085248u          //  2,097,152  u32 addrs[4096][64]
// end: 46,182,400 B

// out layout: probs[B*9] | h1[B*128] | c1[B*128]
#define O_H1 (BATCH * 9)
#define O_C1 (BATCH * 9 + BATCH * LH)

// ---------------------------------------------------------------------------
typedef const __attribute__((address_space(1))) uint32_t* gas_ptr;
typedef __attribute__((address_space(3))) uint32_t* las_ptr;

__device__ __forceinline__ void async16(const void* g, void* l) {
    __builtin_amdgcn_global_load_lds((gas_ptr)g, (las_ptr)l, 16, 0, 0);
}

// ---------------------------------------------------------------------------
// Kernel 1: fused prep.  blocks 0..4095: build_pre (per-row offsets + xtail)
//                        blocks 4096..4607: convert_w
//                        blocks 4608..5207: convert_emb
// ---------------------------------------------------------------------------
__global__ void prep(const int* __restrict__ ab_ids,
                     const int* __restrict__ mv_ids,
                     const float* __restrict__ numerical,
                     const float* __restrict__ h0,
                     const float* __restrict__ numW,
                     const float* __restrict__ numb,
                     const float* __restrict__ Wih,
                     const float* __restrict__ Whh,
                     const float* __restrict__ ab_emb,
                     const float* __restrict__ mv_emb,
                     uint8_t* __restrict__ ws) {
    const int bid = blockIdx.x;
    const int t = threadIdx.x;  // 0..255

    if (bid < BATCH) {
        // ---- build_pre ----
        bf16* xtail = (bf16*)(ws + OFF_XT);
        uint32_t* addrs = (uint32_t*)(ws + OFF_ADDR);
        const int b = bid;

        __shared__ int ids[60];
        __shared__ float numr[84];
        if (t < 60) ids[t] = (t < 12) ? ab_ids[b * 12 + t] : mv_ids[b * 48 + (t - 12)];
        if (t >= 128 && t < 128 + 84) numr[t - 128] = numerical[(size_t)b * 84 + (t - 128)];
        __syncthreads();

        if (t < 128) {
            float acc = numb[t];
#pragma unroll 4
            for (int k = 0; k < 84; ++k)
                acc += numr[k] * numW[t * 84 + k];
            xtail[(size_t)b * 256 + t] = (bf16)acc;
        } else {
            const int tt = t - 128;
            xtail[(size_t)b * 256 + 128 + tt] = (bf16)h0[(size_t)b * LH + tt];
        }

        if (t < 64) {
            uint32_t off;
            if (t < 12) off = OFF_AB + (uint32_t)ids[t] * 256u;
            else if (t < 60) off = OFF_MV + (uint32_t)ids[t] * 256u;
            else if (t == 60) off = OFF_XT + (uint32_t)b * 512u;
            else if (t == 61) off = OFF_XT + (uint32_t)b * 512u + 256u;
            else off = OFF_XT;  // unused slots 62,63
            addrs[(size_t)b * 64 + t] = off;
        }
    } else if (bid < BATCH + 512) {
        // ---- convert_w ----
        bf16* Wcat = (bf16*)(ws + OFF_WCAT);
        const int n = bid - BATCH;
        const float* src_ih = Wih + (size_t)n * KIH;
        const float* src_hh = Whh + (size_t)n * LH;
        bf16* dst = Wcat + (size_t)n * KTOT;
        for (int k4 = t; k4 < KTOT / 4; k4 += 256) {
            const int k = k4 * 4;
            const float4 v = (k < KIH) ? *(const float4*)(src_ih + k)
                                       : *(const float4*)(src_hh + (k - KIH));
            bf16 o0 = (bf16)v.x, o1 = (bf16)v.y, o2 = (bf16)v.z, o3 = (bf16)v.w;
            dst[k] = o0; dst[k + 1] = o1; dst[k + 2] = o2; dst[k + 3] = o3;
        }
    } else {
        // ---- convert_emb ----
        bf16* ab8 = (bf16*)(ws + OFF_AB);
        bf16* mv8 = (bf16*)(ws + OFF_MV);
        const int i = (bid - BATCH - 512) * 256 + t;   // 0..153599
        if (i < 300 * 128) ab8[i] = (bf16)ab_emb[i];
        else if (i < 1200 * 128) mv8[i - 300 * 128] = (bf16)mv_emb[i - 300 * 128];
    }
}

// ---------------------------------------------------------------------------
// Kernel 2: gpart[bz] = x @ Wcat.T partial  (x gathered on the fly)
// 256x128 block tile, BK=64; 4 waves in 2m x 2n, each wave 128x64 (8x4 MFMA
// tiles -> 42.7 FLOP per LDS byte vs 32 for 64x64).  XOR-swizzled LDS,
// double-buffered DMA staging, split-K=4, plain-store partials.  1 block/CU.
// ---------------------------------------------------------------------------
__global__ __launch_bounds__(256, 1) void gemm_gates(
    const uint8_t* __restrict__ wsbase,
    const bf16* __restrict__ Wcat,
    const uint32_t* __restrict__ addrs,
    float* __restrict__ gpart) {
    __shared__ bf16 As[2][256 * 64];    // 2 x 32 KB
    __shared__ bf16 Bs[2][128 * 64];    // 2 x 16 KB
    __shared__ uint32_t adr[16][256];   // 16 KB

    const int tid = threadIdx.x;
    const int w = tid >> 6;       // wave 0..3
    const int lane = tid & 63;
    const int bm = blockIdx.x;    // 0..15 (256 rows)
    const int bn = blockIdx.y;    // 0..3  (128 cols)
    const int bz = blockIdx.z;    // 0..3
    const int kt_beg = bz * 31;
    const int kt_end = kt_beg + 31;
    const int s0 = kt_beg >> 1;   // 31 kts span exactly 16 slots

    for (int i = tid; i < 16 * 256; i += 256)
        adr[i >> 8][i & 255] =
            addrs[(size_t)(bm * 256 + (i & 255)) * 64 + s0 + (i >> 8)];

    const int r_l = lane >> 3;                  // staging row within 8-row group
    const int sc16 = ((lane & 7) ^ r_l) * 16;   // XOR-swizzled 16B chunk (bytes)

    f32x4 acc[8][4];
#pragma unroll
    for (int i = 0; i < 8; ++i)
#pragma unroll
        for (int j = 0; j < 4; ++j)
#pragma unroll
            for (int r = 0; r < 4; ++r) acc[i][j][r] = 0.f;

    const int wm = w & 1, wn = w >> 1;
    const int m0 = wm * 128;     // wave's 128-row range
    const int n0 = wn * 64;      // wave's 64-col range

    __syncthreads();  // adr visible

    auto stage = [&](int kt, int pb) {
        const int k0 = kt * 64;
        const int sl = (kt >> 1) - s0;
        const int hb = (kt & 1) * 128;
        // A: 32 groups of 8 rows, 8 per wave
#pragma unroll
        for (int j = 0; j < 8; ++j) {
            const int g = w * 8 + j;
            const int row = g * 8 + r_l;
            const uint8_t* gsrc = wsbase + adr[sl][row] + hb + sc16;
            async16(gsrc, (void*)&As[pb][(g * 64 + lane) * 8]);
        }
        // B: 16 groups, 4 per wave
#pragma unroll
        for (int j = 0; j < 4; ++j) {
            const int g = w * 4 + j;
            const int row = g * 8 + r_l;
            const bf16* gsrc = Wcat + (size_t)(bn * 128 + row) * KTOT + k0 + (sc16 >> 1);
            async16(gsrc, (void*)&Bs[pb][(g * 64 + lane) * 8]);
        }
    };

    stage(kt_beg, 0);   // prologue into buffer 0

    for (int kt = kt_beg; kt < kt_end; ++kt) {
        const int pb = (kt - kt_beg) & 1;
        __syncthreads();
        if (kt + 1 < kt_end) stage(kt + 1, pb ^ 1);

        const bf16* Ab = &As[pb][0];
        const bf16* Bb = &Bs[pb][0];
#pragma unroll
        for (int ks = 0; ks < 2; ++ks) {
            const int kk8 = ks * 4 + (lane >> 4);       // global column chunk
            bf16x8 bfr[4];
#pragma unroll
            for (int tj = 0; tj < 4; ++tj) {
                const int n = n0 + tj * 16 + (lane & 15);
                bfr[tj] = *(const bf16x8*)&Bb[n * 64 + ((kk8 ^ (n & 7)) * 8)];
            }
#pragma unroll
            for (int ti = 0; ti < 8; ++ti) {
                const int m = m0 + ti * 16 + (lane & 15);
                const bf16x8 af = *(const bf16x8*)&Ab[m * 64 + ((kk8 ^ (m & 7)) * 8)];
#pragma unroll
                for (int tj = 0; tj < 4; ++tj)
                    acc[ti][tj] = __builtin_amdgcn_mfma_f32_16x16x32_bf16(
                        af, bfr[tj], acc[ti][tj], 0, 0, 0);
            }
        }
    }

    // ---- epilogue: plain stores to this bz's partial buffer ----
    float* gdst = gpart + (size_t)bz * BATCH * NG;
    const int mlo = (lane >> 4) * 4;
    const int nlo = lane & 15;
#pragma unroll
    for (int ti = 0; ti < 8; ++ti)
#pragma unroll
        for (int tj = 0; tj < 4; ++tj) {
            const int mg = bm * 256 + m0 + ti * 16 + mlo;
            const int ng = bn * 128 + n0 + tj * 16 + nlo;
            float* dst = gdst + (size_t)mg * NG + ng;
#pragma unroll
            for (int r = 0; r < 4; ++r)
                dst[(size_t)r * NG] = acc[ti][tj][r];
        }
}

// ---------------------------------------------------------------------------
// Kernel 3: fused tail. 256 blocks x 128 threads (2 waves); 16 rows/block.
// Phase A: sum split-K partials + LSTM pointwise -> h1/c1 (fp32 out),
//          h1 bf16 into LDS.
// Phase B: MFMA MLP chain h1 -> u -> feat -> logits, softmax + masked renorm.
// ---------------------------------------------------------------------------
__global__ __launch_bounds__(128, 3) void tail(
    const float* __restrict__ gpart, const float* __restrict__ bih,
    const float* __restrict__ bhh, const float* __restrict__ c0,
    const float* __restrict__ mask,
    const float* __restrict__ W1, const float* __restrict__ b1,
    const float* __restrict__ W2, const float* __restrict__ b2,
    const float* __restrict__ Wa, const float* __restrict__ ba,
    float* __restrict__ out) {
    __shared__ bf16 W1f[8192];    // 16 frags (nt<4,kt<4)
    __shared__ bf16 W2f[8192];    // 16 frags (nt<8,kt<2)
    __shared__ bf16 Waf[2048];    // 4 frags (kt<4)
    __shared__ bf16 h1s[16 * 128];
    __shared__ bf16 uS[16 * 64];
    __shared__ bf16 fS[16 * 128];
    __shared__ float b1s[64];
    __shared__ float b2s[128];
    __shared__ float bas[16];

    const int tid = threadIdx.x;
    const int b0 = blockIdx.x * 16;

    // ---- stage weights as B-fragments: lane holds n=l&15, k=(l>>4)*8+j ----
    for (int e = tid; e < 8192; e += 128) {     // W1 (64x128)
        const int j = e & 7, ln = (e >> 3) & 63, fid = e >> 9;
        const int kt = fid & 3, nt = fid >> 2;
        const int n = nt * 16 + (ln & 15);
        const int k = kt * 32 + (ln >> 4) * 8 + j;
        W1f[e] = (bf16)W1[n * 128 + k];
    }
    for (int e = tid; e < 8192; e += 128) {     // W2 (128x64)
        const int j = e & 7, ln = (e >> 3) & 63, fid = e >> 9;
        const int kt = fid & 1, nt = fid >> 1;
        const int n = nt * 16 + (ln & 15);
        const int k = kt * 32 + (ln >> 4) * 8 + j;
        W2f[e] = (bf16)W2[n * 64 + k];
    }
    for (int e = tid; e < 2048; e += 128) {     // Wa (9x128, zero-padded)
        const int j = e & 7, ln = (e >> 3) & 63, kt = e >> 9;
        const int n = ln & 15;
        const int k = kt * 32 + (ln >> 4) * 8 + j;
        Waf[e] = (n < 9) ? (bf16)Wa[n * 128 + k] : (bf16)0.f;
    }
    if (tid < 64) b1s[tid] = b1[tid];
    if (tid < 16) bas[tid] = (tid < 9) ? ba[tid] : 0.f;
    if (tid < 128) b2s[tid] = b2[tid];

    // ---- phase A: gates -> h1/c1 for 16 rows ----
#pragma unroll
    for (int i = 0; i < 16; ++i) {
        const int p = tid + 128 * i;        // (row, unit) pair
        const int uu = p & 127;
        const int r = p >> 7;
        const int b = b0 + r;
        float gv[4];
#pragma unroll
        for (int q = 0; q < 4; ++q)
            gv[q] = bih[q * 128 + uu] + bhh[q * 128 + uu];
#pragma unroll
        for (int z = 0; z < SPLITK; ++z) {
            const float* gz = gpart + ((size_t)z * BATCH + b) * NG + uu;
#pragma unroll
            for (int q = 0; q < 4; ++q) gv[q] += gz[q * 128];
        }
        const float iv = 1.f / (1.f + __expf(-gv[0]));
        const float fv = 1.f / (1.f + __expf(-gv[1]));
        const float gg = tanhf(gv[2]);
        const float ov = 1.f / (1.f + __expf(-gv[3]));
        const float c1 = fv * c0[(size_t)b * LH + uu] + iv * gg;
        const float h1 = ov * tanhf(c1);
        out[O_H1 + (size_t)b * LH + uu] = h1;
        out[O_C1 + (size_t)b * LH + uu] = c1;
        h1s[r * 128 + uu] = (bf16)h1;
    }
    __syncthreads();

    const int wv = tid >> 6, lane = tid & 63;
    const int nl = lane & 15, kg = lane >> 4;

    // ---- A-frags of h1 tile (16x128) ----
    bf16x8 ah[4];
#pragma unroll
    for (int kt = 0; kt < 4; ++kt)
        ah[kt] = *(const bf16x8*)&h1s[nl * 128 + kt * 32 + kg * 8];

    // ---- stage 1: u = relu(h1 @ W1^T + b1) (16x64); waves split nt ----
#pragma unroll
    for (int t2 = 0; t2 < 2; ++t2) {
        const int nt = wv * 2 + t2;
        f32x4 a = {0.f, 0.f, 0.f, 0.f};
#pragma unroll
        for (int kt = 0; kt < 4; ++kt)
            a = __builtin_amdgcn_mfma_f32_16x16x32_bf16(
                ah[kt], *(const bf16x8*)&W1f[((nt * 4 + kt) * 64 + lane) * 8], a, 0, 0, 0);
        const int n = nt * 16 + nl;
#pragma unroll
        for (int r = 0; r < 4; ++r)
            uS[(kg * 4 + r) * 64 + n] = (bf16)fmaxf(a[r] + b1s[n], 0.f);
    }
    __syncthreads();

    bf16x8 au[2];
#pragma unroll
    for (int kt = 0; kt < 2; ++kt)
        au[kt] = *(const bf16x8*)&uS[nl * 64 + kt * 32 + kg * 8];

    // ---- stage 2: feat = u @ W2^T + b2 (16x128); waves split nt ----
#pragma unroll
    for (int t2 = 0; t2 < 4; ++t2) {
        const int nt = wv * 4 + t2;
        f32x4 a = {0.f, 0.f, 0.f, 0.f};
#pragma unroll
        for (int kt = 0; kt < 2; ++kt)
            a = __builtin_amdgcn_mfma_f32_16x16x32_bf16(
                au[kt], *(const bf16x8*)&W2f[((nt * 2 + kt) * 64 + lane) * 8], a, 0, 0, 0);
        const int n = nt * 16 + nl;
#pragma unroll
        for (int r = 0; r < 4; ++r)
            fS[(kg * 4 + r) * 128 + n] = (bf16)(a[r] + b2s[n]);
    }
    __syncthreads();

    // ---- stage 3 + softmax: wave 0 only ----
    if (wv == 0) {
        bf16x8 afr[4];
#pragma unroll
        for (int kt = 0; kt < 4; ++kt)
            afr[kt] = *(const bf16x8*)&fS[nl * 128 + kt * 32 + kg * 8];

        f32x4 lg4 = {0.f, 0.f, 0.f, 0.f};
#pragma unroll
        for (int kt = 0; kt < 4; ++kt)
            lg4 = __builtin_amdgcn_mfma_f32_16x16x32_bf16(
                afr[kt], *(const bf16x8*)&Waf[(kt * 64 + lane) * 8], lg4, 0, 0, 0);

#pragma unroll
        for (int r = 0; r < 4; ++r) {
            const int b = b0 + kg * 4 + r;
            float lg = (nl < 9) ? lg4[r] + bas[nl] : -1e30f;
            float mx = lg;
#pragma unroll
            for (int off = 1; off < 16; off <<= 1)
                mx = fmaxf(mx, __shfl_xor(mx, off, 64));
            const float e = (nl < 9) ? __expf(lg - mx) : 0.f;
            const float mv = (nl < 9) ? mask[(size_t)b * 9 + nl] : 0.f;
            float tot = e, ms = e * mv;
#pragma unroll
            for (int off = 1; off < 16; off <<= 1) {
                tot += __shfl_xor(tot, off, 64);
                ms += __shfl_xor(ms, off, 64);
            }
            if (nl < 9)
                out[(size_t)b * 9 + nl] = (ms > 0.f) ? e * mv / ms : e / tot;
        }
    }
}

// ---------------------------------------------------------------------------
extern "C" void kernel_launch(void* const* d_in, const int* in_sizes, int n_in,
                              void* d_out, int out_size, void* d_ws, size_t ws_size,
                              hipStream_t stream) {
    const int* ab_ids = (const int*)d_in[0];
    const int* mv_ids = (const int*)d_in[1];
    const float* numerical = (const float*)d_in[2];
    const float* mask = (const float*)d_in[3];
    const float* h0 = (const float*)d_in[4];
    const float* c0 = (const float*)d_in[5];
    const float* ab_emb = (const float*)d_in[6];
    const float* mv_emb = (const float*)d_in[7];
    const float* numW = (const float*)d_in[8];
    const float* numb = (const float*)d_in[9];
    const float* Wih = (const float*)d_in[10];
    const float* Whh = (const float*)d_in[11];
    const float* bih = (const float*)d_in[12];
    const float* bhh = (const float*)d_in[13];
    const float* W1 = (const float*)d_in[14];
    const float* b1 = (const float*)d_in[15];
    const float* W2 = (const float*)d_in[16];
    const float* b2 = (const float*)d_in[17];
    const float* Wa = (const float*)d_in[18];
    const float* ba = (const float*)d_in[19];
    float* out = (float*)d_out;

    uint8_t* ws = (uint8_t*)d_ws;
    bf16* Wcat = (bf16*)(ws + OFF_WCAT);
    float* gpart = (float*)(ws + OFF_GPART);
    uint32_t* addrs = (uint32_t*)(ws + OFF_ADDR);

    prep<<<BATCH + 512 + 600, 256, 0, stream>>>(
        ab_ids, mv_ids, numerical, h0, numW, numb, Wih, Whh, ab_emb, mv_emb, ws);
    gemm_gates<<<dim3(16, 4, SPLITK), 256, 0, stream>>>(ws, Wcat, addrs, gpart);
    tail<<<BATCH / 16, 128, 0, stream>>>(gpart, bih, bhh, c0, mask,
                                         W1, b1, W2, b2, Wa, ba, out);
}

// Round 11
// 182.244 us; speedup vs baseline: 1.4418x; 1.0934x over previous
//
#include <hip/hip_runtime.h>
#include <hip/hip_bf16.h>
#include <stdint.h>
#include <stddef.h>

typedef __bf16 bf16;
typedef __bf16 bf16x8 __attribute__((ext_vector_type(8)));
typedef float f32x4 __attribute__((ext_vector_type(4)));

#define BATCH 4096
#define KIH 7808          // Wih K
#define KTOT 7936         // 62 slots * 128 (h0 appended)
#define NG 512            // 4*LH gates
#define LH 128
#define HD 64
#define ED 128
#define SPLITK 4

// workspace layout (byte offsets)
#define OFF_WCAT 0u                 //  8,126,464  bf16 Wcat[512][7936]
#define OFF_GPART 8126464u          // 33,554,432  f32 gpart[4][4096][512]
#define OFF_XT   41680896u          //  2,097,152  bf16 xtail[4096][256]
#define OFF_AB   43778048u          //     76,800  bf16 ab8[300][128]
#define OFF_MV   43854848u          //    230,400  bf16 mv8[900][128]
#define OFF_ADDR 44085248u          //  2,097,152  u32 addrs[4096][64]
#define OFF_H1B  46182400u          //  1,048,576  bf16 h1b[4096][128]
#define OFF_W1F  47230976u          //     16,384  bf16 W1 fragments
#define OFF_W2F  47247360u          //     16,384  bf16 W2 fragments
#define OFF_WAF  47263744u          //      4,096  bf16 Wa fragments
// end: 47,267,840 B

// out layout: probs[B*9] | h1[B*128] | c1[B*128]
#define O_H1 (BATCH * 9)
#define O_C1 (BATCH * 9 + BATCH * LH)

// ---------------------------------------------------------------------------
typedef const __attribute__((address_space(1))) uint32_t* gas_ptr;
typedef __attribute__((address_space(3))) uint32_t* las_ptr;

__device__ __forceinline__ void async16(const void* g, void* l) {
    __builtin_amdgcn_global_load_lds((gas_ptr)g, (las_ptr)l, 16, 0, 0);
}

// ---------------------------------------------------------------------------
// Kernel 1: fused prep.
//   blocks 0..4095:      build_pre (per-row offsets + xtail)
//   blocks 4096..4607:   convert_w
//   blocks 4608..5207:   convert_emb
//   block  5208:         pack MLP weight fragments
// ---------------------------------------------------------------------------
__global__ void prep(const int* __restrict__ ab_ids,
                     const int* __restrict__ mv_ids,
                     const float* __restrict__ numerical,
                     const float* __restrict__ h0,
                     const float* __restrict__ numW,
                     const float* __restrict__ numb,
                     const float* __restrict__ Wih,
                     const float* __restrict__ Whh,
                     const float* __restrict__ ab_emb,
                     const float* __restrict__ mv_emb,
                     const float* __restrict__ W1,
                     const float* __restrict__ W2,
                     const float* __restrict__ Wa,
                     uint8_t* __restrict__ ws) {
    const int bid = blockIdx.x;
    const int t = threadIdx.x;  // 0..255

    if (bid < BATCH) {
        // ---- build_pre ----
        bf16* xtail = (bf16*)(ws + OFF_XT);
        uint32_t* addrs = (uint32_t*)(ws + OFF_ADDR);
        const int b = bid;

        __shared__ int ids[60];
        __shared__ float numr[84];
        if (t < 60) ids[t] = (t < 12) ? ab_ids[b * 12 + t] : mv_ids[b * 48 + (t - 12)];
        if (t >= 128 && t < 128 + 84) numr[t - 128] = numerical[(size_t)b * 84 + (t - 128)];
        __syncthreads();

        if (t < 128) {
            float acc = numb[t];
#pragma unroll 4
            for (int k = 0; k < 84; ++k)
                acc += numr[k] * numW[t * 84 + k];
            xtail[(size_t)b * 256 + t] = (bf16)acc;
        } else {
            const int tt = t - 128;
            xtail[(size_t)b * 256 + 128 + tt] = (bf16)h0[(size_t)b * LH + tt];
        }

        if (t < 64) {
            uint32_t off;
            if (t < 12) off = OFF_AB + (uint32_t)ids[t] * 256u;
            else if (t < 60) off = OFF_MV + (uint32_t)ids[t] * 256u;
            else if (t == 60) off = OFF_XT + (uint32_t)b * 512u;
            else if (t == 61) off = OFF_XT + (uint32_t)b * 512u + 256u;
            else off = OFF_XT;  // unused slots 62,63
            addrs[(size_t)b * 64 + t] = off;
        }
    } else if (bid < BATCH + 512) {
        // ---- convert_w ----
        bf16* Wcat = (bf16*)(ws + OFF_WCAT);
        const int n = bid - BATCH;
        const float* src_ih = Wih + (size_t)n * KIH;
        const float* src_hh = Whh + (size_t)n * LH;
        bf16* dst = Wcat + (size_t)n * KTOT;
        for (int k4 = t; k4 < KTOT / 4; k4 += 256) {
            const int k = k4 * 4;
            const float4 v = (k < KIH) ? *(const float4*)(src_ih + k)
                                       : *(const float4*)(src_hh + (k - KIH));
            bf16 o0 = (bf16)v.x, o1 = (bf16)v.y, o2 = (bf16)v.z, o3 = (bf16)v.w;
            dst[k] = o0; dst[k + 1] = o1; dst[k + 2] = o2; dst[k + 3] = o3;
        }
    } else if (bid < BATCH + 512 + 600) {
        // ---- convert_emb ----
        bf16* ab8 = (bf16*)(ws + OFF_AB);
        bf16* mv8 = (bf16*)(ws + OFF_MV);
        const int i = (bid - BATCH - 512) * 256 + t;   // 0..153599
        if (i < 300 * 128) ab8[i] = (bf16)ab_emb[i];
        else if (i < 1200 * 128) mv8[i - 300 * 128] = (bf16)mv_emb[i - 300 * 128];
    } else {
        // ---- pack MLP weight fragments (B-frag: lane n=l&15, k=(l>>4)*8+j) --
        bf16* W1f = (bf16*)(ws + OFF_W1F);
        bf16* W2f = (bf16*)(ws + OFF_W2F);
        bf16* Waf = (bf16*)(ws + OFF_WAF);
        for (int e = t; e < 8192; e += 256) {     // W1 (64x128), fid = nt*4+kt
            const int j = e & 7, ln = (e >> 3) & 63, fid = e >> 9;
            const int kt = fid & 3, nt = fid >> 2;
            const int n = nt * 16 + (ln & 15);
            const int k = kt * 32 + (ln >> 4) * 8 + j;
            W1f[e] = (bf16)W1[n * 128 + k];
        }
        for (int e = t; e < 8192; e += 256) {     // W2 (128x64), fid = nt*2+kt
            const int j = e & 7, ln = (e >> 3) & 63, fid = e >> 9;
            const int kt = fid & 1, nt = fid >> 1;
            const int n = nt * 16 + (ln & 15);
            const int k = kt * 32 + (ln >> 4) * 8 + j;
            W2f[e] = (bf16)W2[n * 64 + k];
        }
        for (int e = t; e < 2048; e += 256) {     // Wa (9x128 zero-padded)
            const int j = e & 7, ln = (e >> 3) & 63, kt = e >> 9;
            const int n = ln & 15;
            const int k = kt * 32 + (ln >> 4) * 8 + j;
            Waf[e] = (n < 9) ? (bf16)Wa[n * 128 + k] : (bf16)0.f;
        }
    }
}

// ---------------------------------------------------------------------------
// Kernel 2: gpart[bz] = x @ Wcat.T partial  (x gathered on the fly)
// 128x128 tile, BK=64, XOR-swizzled LDS, double-buffered, split-K=4,
// plain-store partials.  (round-7 proven config: 49.4 us)
// ---------------------------------------------------------------------------
__global__ __launch_bounds__(256, 2) void gemm_gates(
    const uint8_t* __restrict__ wsbase,
    const bf16* __restrict__ Wcat,
    const uint32_t* __restrict__ addrs,
    float* __restrict__ gpart) {
    __shared__ bf16 As[2][128 * 64];    // 2 x 16 KB
    __shared__ bf16 Bs[2][128 * 64];    // 2 x 16 KB
    __shared__ uint32_t adr[17][128];   // 8.5 KB

    const int tid = threadIdx.x;
    const int w = tid >> 6;       // wave 0..3
    const int lane = tid & 63;
    const int bm = blockIdx.x;    // 0..31
    const int bn = blockIdx.y;    // 0..3
    const int bz = blockIdx.z;    // 0..3
    const int kt_beg = bz * 31;
    const int kt_end = kt_beg + 31;

    // preload this block's (row, slot) offsets
    const int s0 = kt_beg >> 1;
    const int ns = ((kt_end - 1) >> 1) - s0 + 1;   // <= 17
    for (int i = tid; i < ns * 128; i += 256) {
        adr[i >> 7][i & 127] =
            addrs[(size_t)(bm * 128 + (i & 127)) * 64 + s0 + (i >> 7)];
    }

    const int r_l = lane >> 3;                  // staging row within 8-row group
    const int sc16 = ((lane & 7) ^ r_l) * 16;   // XOR-swizzled 16B chunk (bytes)

    f32x4 acc[4][4];
#pragma unroll
    for (int i = 0; i < 4; ++i)
#pragma unroll
        for (int j = 0; j < 4; ++j)
#pragma unroll
            for (int r = 0; r < 4; ++r) acc[i][j][r] = 0.f;

    const int m0 = (w & 1) * 64;
    const int n0 = (w >> 1) * 64;

    __syncthreads();  // adr visible

    auto stage = [&](int kt, int pb) {
        const int k0 = kt * 64;
        const int sl = (kt >> 1) - s0;
        const int hb = (kt & 1) * 128;
#pragma unroll
        for (int j = 0; j < 4; ++j) {
            const int row = (w * 4 + j) * 8 + r_l;
            const uint8_t* gsrc = wsbase + adr[sl][row] + hb + sc16;
            async16(gsrc, (void*)&As[pb][((w * 4 + j) * 64 + lane) * 8]);
        }
#pragma unroll
        for (int j = 0; j < 4; ++j) {
            const int row = (w * 4 + j) * 8 + r_l;
            const bf16* gsrc = Wcat + (size_t)(bn * 128 + row) * KTOT + k0 + (sc16 >> 1);
            async16(gsrc, (void*)&Bs[pb][((w * 4 + j) * 64 + lane) * 8]);
        }
    };

    stage(kt_beg, 0);   // prologue into buffer 0

    for (int kt = kt_beg; kt < kt_end; ++kt) {
        const int pb = (kt - kt_beg) & 1;
        __syncthreads();
        if (kt + 1 < kt_end) stage(kt + 1, pb ^ 1);

        const bf16* Ab = &As[pb][0];
        const bf16* Bb = &Bs[pb][0];
#pragma unroll
        for (int ks = 0; ks < 2; ++ks) {
            bf16x8 af[4], bfr[4];
            const int kk8 = ks * 4 + (lane >> 4);       // global column chunk
#pragma unroll
            for (int t = 0; t < 4; ++t) {
                const int m = m0 + t * 16 + (lane & 15);
                af[t] = *(const bf16x8*)&Ab[m * 64 + ((kk8 ^ (m & 7)) * 8)];
                const int n = n0 + t * 16 + (lane & 15);
                bfr[t] = *(const bf16x8*)&Bb[n * 64 + ((kk8 ^ (n & 7)) * 8)];
            }
#pragma unroll
            for (int ti = 0; ti < 4; ++ti)
#pragma unroll
                for (int tj = 0; tj < 4; ++tj)
                    acc[ti][tj] = __builtin_amdgcn_mfma_f32_16x16x32_bf16(
                        af[ti], bfr[tj], acc[ti][tj], 0, 0, 0);
        }
    }

    // ---- epilogue: plain stores to this bz's partial buffer ----
    float* gdst = gpart + (size_t)bz * BATCH * NG;
    const int mlo = (lane >> 4) * 4;
    const int nlo = lane & 15;
#pragma unroll
    for (int ti = 0; ti < 4; ++ti)
#pragma unroll
        for (int tj = 0; tj < 4; ++tj) {
            const int mg = bm * 128 + m0 + ti * 16 + mlo;
            const int ng = bn * 128 + n0 + tj * 16 + nlo;
            float* dst = gdst + (size_t)mg * NG + ng;
#pragma unroll
            for (int r = 0; r < 4; ++r)
                dst[(size_t)r * NG] = acc[ti][tj][r];
        }
}

// ---------------------------------------------------------------------------
// Kernel 3: reduce split-K partials + LSTM pointwise.
// 2048 blocks x 256 threads; 2 rows/block, 1 thread per LSTM unit.
// Writes h1/c1 (fp32, d_out) and h1b (bf16 scratch for the MLP head).
// ---------------------------------------------------------------------------
__global__ void reduce_lstm(const float* __restrict__ gpart,
                            const float* __restrict__ bih,
                            const float* __restrict__ bhh,
                            const float* __restrict__ c0,
                            float* __restrict__ out,
                            bf16* __restrict__ h1b) {
    const int t = threadIdx.x;
    const int b = blockIdx.x * 2 + (t >> 7);
    const int u = t & 127;

    float gv[4];
#pragma unroll
    for (int q = 0; q < 4; ++q)
        gv[q] = bih[q * 128 + u] + bhh[q * 128 + u];
#pragma unroll
    for (int z = 0; z < SPLITK; ++z) {
        const float* gz = gpart + ((size_t)z * BATCH + b) * NG + u;
#pragma unroll
        for (int q = 0; q < 4; ++q) gv[q] += gz[q * 128];
    }

    const float iv = 1.f / (1.f + __expf(-gv[0]));
    const float fv = 1.f / (1.f + __expf(-gv[1]));
    const float gg = tanhf(gv[2]);
    const float ov = 1.f / (1.f + __expf(-gv[3]));
    const float c1 = fv * c0[(size_t)b * LH + u] + iv * gg;
    const float h1 = ov * tanhf(c1);

    out[O_H1 + (size_t)b * LH + u] = h1;
    out[O_C1 + (size_t)b * LH + u] = c1;
    h1b[(size_t)b * LH + u] = (bf16)h1;
}

// ---------------------------------------------------------------------------
// Kernel 4: MLP head, 1 wave per block, 16 rows/block, 256 blocks.
// All weight B-fragments read straight global->VGPR from the pre-packed
// L2-resident arrays (no staging preamble, no multi-wave barriers).
// LDS only for u/feat C->A relayout (6 KB).
// ---------------------------------------------------------------------------
__global__ __launch_bounds__(64) void mlp_head(
    const bf16* __restrict__ h1b, const float* __restrict__ mask,
    const bf16* __restrict__ W1f, const bf16* __restrict__ W2f,
    const bf16* __restrict__ Waf,
    const float* __restrict__ b1, const float* __restrict__ b2,
    const float* __restrict__ ba,
    float* __restrict__ out) {
    __shared__ bf16 uS[16 * 64];     // 2 KB
    __shared__ bf16 fS[16 * 128];    // 4 KB

    const int lane = threadIdx.x;    // 0..63
    const int b0 = blockIdx.x * 16;
    const int nl = lane & 15, kg = lane >> 4;

    // A-frags of the 16x128 h1 tile
    bf16x8 ah[4];
#pragma unroll
    for (int kt = 0; kt < 4; ++kt)
        ah[kt] = *(const bf16x8*)&h1b[(size_t)(b0 + nl) * 128 + kt * 32 + kg * 8];

    // ---- stage 1: u = relu(h1 @ W1^T + b1)  (16x64) ----
#pragma unroll
    for (int nt = 0; nt < 4; ++nt) {
        f32x4 a = {0.f, 0.f, 0.f, 0.f};
#pragma unroll
        for (int kt = 0; kt < 4; ++kt)
            a = __builtin_amdgcn_mfma_f32_16x16x32_bf16(
                ah[kt], *(const bf16x8*)&W1f[((nt * 4 + kt) * 64 + lane) * 8],
                a, 0, 0, 0);
        const int n = nt * 16 + nl;
        const float bb = b1[n];
#pragma unroll
        for (int r = 0; r < 4; ++r)
            uS[(kg * 4 + r) * 64 + n] = (bf16)fmaxf(a[r] + bb, 0.f);
    }
    __syncthreads();   // single wave: just orders LDS

    bf16x8 au[2];
#pragma unroll
    for (int kt = 0; kt < 2; ++kt)
        au[kt] = *(const bf16x8*)&uS[nl * 64 + kt * 32 + kg * 8];

    // ---- stage 2: feat = u @ W2^T + b2  (16x128) ----
#pragma unroll
    for (int nt = 0; nt < 8; ++nt) {
        f32x4 a = {0.f, 0.f, 0.f, 0.f};
#pragma unroll
        for (int kt = 0; kt < 2; ++kt)
            a = __builtin_amdgcn_mfma_f32_16x16x32_bf16(
                au[kt], *(const bf16x8*)&W2f[((nt * 2 + kt) * 64 + lane) * 8],
                a, 0, 0, 0);
        const int n = nt * 16 + nl;
        const float bb = b2[n];
#pragma unroll
        for (int r = 0; r < 4; ++r)
            fS[(kg * 4 + r) * 128 + n] = (bf16)(a[r] + bb);
    }
    __syncthreads();

    bf16x8 afr[4];
#pragma unroll
    for (int kt = 0; kt < 4; ++kt)
        afr[kt] = *(const bf16x8*)&fS[nl * 128 + kt * 32 + kg * 8];

    // ---- stage 3: logits = feat @ Wa^T + ba  (16x16, 9 valid) ----
    f32x4 lg4 = {0.f, 0.f, 0.f, 0.f};
#pragma unroll
    for (int kt = 0; kt < 4; ++kt)
        lg4 = __builtin_amdgcn_mfma_f32_16x16x32_bf16(
            afr[kt], *(const bf16x8*)&Waf[(kt * 64 + lane) * 8], lg4, 0, 0, 0);

    const float bav = (nl < 9) ? ba[nl] : 0.f;

    // ---- softmax + masked renorm; row m = kg*4+r, action = nl ----
#pragma unroll
    for (int r = 0; r < 4; ++r) {
        const int b = b0 + kg * 4 + r;
        float lg = (nl < 9) ? lg4[r] + bav : -1e30f;
        float mx = lg;
#pragma unroll
        for (int off = 1; off < 16; off <<= 1)
            mx = fmaxf(mx, __shfl_xor(mx, off, 64));
        const float e = (nl < 9) ? __expf(lg - mx) : 0.f;
        const float mv = (nl < 9) ? mask[(size_t)b * 9 + nl] : 0.f;
        float tot = e, ms = e * mv;
#pragma unroll
        for (int off = 1; off < 16; off <<= 1) {
            tot += __shfl_xor(tot, off, 64);
            ms += __shfl_xor(ms, off, 64);
        }
        if (nl < 9)
            out[(size_t)b * 9 + nl] = (ms > 0.f) ? e * mv / ms : e / tot;
    }
}

// ---------------------------------------------------------------------------
extern "C" void kernel_launch(void* const* d_in, const int* in_sizes, int n_in,
                              void* d_out, int out_size, void* d_ws, size_t ws_size,
                              hipStream_t stream) {
    const int* ab_ids = (const int*)d_in[0];
    const int* mv_ids = (const int*)d_in[1];
    const float* numerical = (const float*)d_in[2];
    const float* mask = (const float*)d_in[3];
    const float* h0 = (const float*)d_in[4];
    const float* c0 = (const float*)d_in[5];
    const float* ab_emb = (const float*)d_in[6];
    const float* mv_emb = (const float*)d_in[7];
    const float* numW = (const float*)d_in[8];
    const float* numb = (const float*)d_in[9];
    const float* Wih = (const float*)d_in[10];
    const float* Whh = (const float*)d_in[11];
    const float* bih = (const float*)d_in[12];
    const float* bhh = (const float*)d_in[13];
    const float* W1 = (const float*)d_in[14];
    const float* b1 = (const float*)d_in[15];
    const float* W2 = (const float*)d_in[16];
    const float* b2 = (const float*)d_in[17];
    const float* Wa = (const float*)d_in[18];
    const float* ba = (const float*)d_in[19];
    float* out = (float*)d_out;

    uint8_t* ws = (uint8_t*)d_ws;
    bf16* Wcat = (bf16*)(ws + OFF_WCAT);
    float* gpart = (float*)(ws + OFF_GPART);
    uint32_t* addrs = (uint32_t*)(ws + OFF_ADDR);
    bf16* h1b = (bf16*)(ws + OFF_H1B);
    bf16* W1f = (bf16*)(ws + OFF_W1F);
    bf16* W2f = (bf16*)(ws + OFF_W2F);
    bf16* Waf = (bf16*)(ws + OFF_WAF);

    prep<<<BATCH + 512 + 600 + 1, 256, 0, stream>>>(
        ab_ids, mv_ids, numerical, h0, numW, numb, Wih, Whh, ab_emb, mv_emb,
        W1, W2, Wa, ws);
    gemm_gates<<<dim3(32, 4, SPLITK), 256, 0, stream>>>(ws, Wcat, addrs, gpart);
    reduce_lstm<<<BATCH / 2, 256, 0, stream>>>(gpart, bih, bhh, c0, out, h1b);
    mlp_head<<<BATCH / 16, 64, 0, stream>>>(h1b, mask, W1f, W2f, Waf,
                                            b1, b2, ba, out);
}

// Round 12
// 181.048 us; speedup vs baseline: 1.4514x; 1.0066x over previous
//
#include <hip/hip_runtime.h>
#include <hip/hip_bf16.h>
#include <stdint.h>
#include <stddef.h>

typedef __bf16 bf16;
typedef __bf16 bf16x8 __attribute__((ext_vector_type(8)));
typedef float f32x4 __attribute__((ext_vector_type(4)));

#define BATCH 4096
#define KIH 7808          // Wih K
#define KTOT 7936         // 62 slots * 128 (h0 appended)
#define NG 512            // 4*LH gates
#define LH 128
#define HD 64
#define ED 128
#define SPLITK 4

// workspace layout (byte offsets)
#define OFF_WCAT 0u                 //  8,126,464  bf16 Wcat[512][7936]
#define OFF_GPART 8126464u          // 33,554,432  f32 gpart[4][4096][512]
#define OFF_XT   41680896u          //  2,097,152  bf16 xtail[4096][256]
#define OFF_AB   43778048u          //     76,800  bf16 ab8[300][128]
#define OFF_MV   43854848u          //    230,400  bf16 mv8[900][128]
#define OFF_ADDR 44085248u          //  2,097,152  u32 addrs[4096][64]
#define OFF_H1B  46182400u          //  1,048,576  bf16 h1b[4096][128]
#define OFF_W1F  47230976u          //     16,384  bf16 W1 fragments
#define OFF_W2F  47247360u          //     16,384  bf16 W2 fragments
#define OFF_WAF  47263744u          //      4,096  bf16 Wa fragments
// end: 47,267,840 B

// out layout: probs[B*9] | h1[B*128] | c1[B*128]
#define O_H1 (BATCH * 9)
#define O_C1 (BATCH * 9 + BATCH * LH)

// ---------------------------------------------------------------------------
typedef const __attribute__((address_space(1))) uint32_t* gas_ptr;
typedef __attribute__((address_space(3))) uint32_t* las_ptr;

__device__ __forceinline__ void async16(const void* g, void* l) {
    __builtin_amdgcn_global_load_lds((gas_ptr)g, (las_ptr)l, 16, 0, 0);
}

// ---------------------------------------------------------------------------
// Kernel 1: fused prep.
//   blocks 0..4095:      build_pre (per-row offsets + xtail)
//   blocks 4096..4607:   convert_w
//   blocks 4608..5207:   convert_emb
//   block  5208:         pack MLP weight fragments
// ---------------------------------------------------------------------------
__global__ void prep(const int* __restrict__ ab_ids,
                     const int* __restrict__ mv_ids,
                     const float* __restrict__ numerical,
                     const float* __restrict__ h0,
                     const float* __restrict__ numW,
                     const float* __restrict__ numb,
                     const float* __restrict__ Wih,
                     const float* __restrict__ Whh,
                     const float* __restrict__ ab_emb,
                     const float* __restrict__ mv_emb,
                     const float* __restrict__ W1,
                     const float* __restrict__ W2,
                     const float* __restrict__ Wa,
                     uint8_t* __restrict__ ws) {
    const int bid = blockIdx.x;
    const int t = threadIdx.x;  // 0..255

    if (bid < BATCH) {
        // ---- build_pre ----
        bf16* xtail = (bf16*)(ws + OFF_XT);
        uint32_t* addrs = (uint32_t*)(ws + OFF_ADDR);
        const int b = bid;

        __shared__ int ids[60];
        __shared__ float numr[84];
        if (t < 60) ids[t] = (t < 12) ? ab_ids[b * 12 + t] : mv_ids[b * 48 + (t - 12)];
        if (t >= 128 && t < 128 + 84) numr[t - 128] = numerical[(size_t)b * 84 + (t - 128)];
        __syncthreads();

        if (t < 128) {
            float acc = numb[t];
#pragma unroll 4
            for (int k = 0; k < 84; ++k)
                acc += numr[k] * numW[t * 84 + k];
            xtail[(size_t)b * 256 + t] = (bf16)acc;
        } else {
            const int tt = t - 128;
            xtail[(size_t)b * 256 + 128 + tt] = (bf16)h0[(size_t)b * LH + tt];
        }

        if (t < 64) {
            uint32_t off;
            if (t < 12) off = OFF_AB + (uint32_t)ids[t] * 256u;
            else if (t < 60) off = OFF_MV + (uint32_t)ids[t] * 256u;
            else if (t == 60) off = OFF_XT + (uint32_t)b * 512u;
            else if (t == 61) off = OFF_XT + (uint32_t)b * 512u + 256u;
            else off = OFF_XT;  // unused slots 62,63
            addrs[(size_t)b * 64 + t] = off;
        }
    } else if (bid < BATCH + 512) {
        // ---- convert_w ----
        bf16* Wcat = (bf16*)(ws + OFF_WCAT);
        const int n = bid - BATCH;
        const float* src_ih = Wih + (size_t)n * KIH;
        const float* src_hh = Whh + (size_t)n * LH;
        bf16* dst = Wcat + (size_t)n * KTOT;
        for (int k4 = t; k4 < KTOT / 4; k4 += 256) {
            const int k = k4 * 4;
            const float4 v = (k < KIH) ? *(const float4*)(src_ih + k)
                                       : *(const float4*)(src_hh + (k - KIH));
            bf16 o0 = (bf16)v.x, o1 = (bf16)v.y, o2 = (bf16)v.z, o3 = (bf16)v.w;
            dst[k] = o0; dst[k + 1] = o1; dst[k + 2] = o2; dst[k + 3] = o3;
        }
    } else if (bid < BATCH + 512 + 600) {
        // ---- convert_emb ----
        bf16* ab8 = (bf16*)(ws + OFF_AB);
        bf16* mv8 = (bf16*)(ws + OFF_MV);
        const int i = (bid - BATCH - 512) * 256 + t;   // 0..153599
        if (i < 300 * 128) ab8[i] = (bf16)ab_emb[i];
        else if (i < 1200 * 128) mv8[i - 300 * 128] = (bf16)mv_emb[i - 300 * 128];
    } else {
        // ---- pack MLP weight fragments (B-frag: lane n=l&15, k=(l>>4)*8+j) --
        bf16* W1f = (bf16*)(ws + OFF_W1F);
        bf16* W2f = (bf16*)(ws + OFF_W2F);
        bf16* Waf = (bf16*)(ws + OFF_WAF);
        for (int e = t; e < 8192; e += 256) {     // W1 (64x128), fid = nt*4+kt
            const int j = e & 7, ln = (e >> 3) & 63, fid = e >> 9;
            const int kt = fid & 3, nt = fid >> 2;
            const int n = nt * 16 + (ln & 15);
            const int k = kt * 32 + (ln >> 4) * 8 + j;
            W1f[e] = (bf16)W1[n * 128 + k];
        }
        for (int e = t; e < 8192; e += 256) {     // W2 (128x64), fid = nt*2+kt
            const int j = e & 7, ln = (e >> 3) & 63, fid = e >> 9;
            const int kt = fid & 1, nt = fid >> 1;
            const int n = nt * 16 + (ln & 15);
            const int k = kt * 32 + (ln >> 4) * 8 + j;
            W2f[e] = (bf16)W2[n * 64 + k];
        }
        for (int e = t; e < 2048; e += 256) {     // Wa (9x128 zero-padded)
            const int j = e & 7, ln = (e >> 3) & 63, kt = e >> 9;
            const int n = ln & 15;
            const int k = kt * 32 + (ln >> 4) * 8 + j;
            Waf[e] = (n < 9) ? (bf16)Wa[n * 128 + k] : (bf16)0.f;
        }
    }
}

// ---------------------------------------------------------------------------
// Kernel 2: gpart[bz] = x @ Wcat.T partial  (x gathered on the fly)
// 128x128 block tile, BK=64, XOR-swizzled LDS, double-buffered, split-K=4.
// INTRA-BLOCK K-SPLIT: 4 waves = 2 n-halves (wn) x 2 k-slices (wk); each
// wave computes a 128x64 output over its 32-elem k-slice of every BK tile
// -> 12 KB LDS frag reads per wave-kt (vs 16 KB for 64x64 waves) at
// unchanged 8 waves/CU.  wk-partials reduced through LDS at the end.
// ---------------------------------------------------------------------------
__global__ __launch_bounds__(256, 2) void gemm_gates(
    const uint8_t* __restrict__ wsbase,
    const bf16* __restrict__ Wcat,
    const uint32_t* __restrict__ addrs,
    float* __restrict__ gpart) {
    __shared__ bf16 As[2][128 * 64];    // 2 x 16 KB
    __shared__ bf16 Bs[2][128 * 64];    // 2 x 16 KB
    __shared__ uint32_t adr[17][128];   // 8.5 KB

    const int tid = threadIdx.x;
    const int w = tid >> 6;       // wave 0..3
    const int lane = tid & 63;
    const int bm = blockIdx.x;    // 0..31
    const int bn = blockIdx.y;    // 0..3
    const int bz = blockIdx.z;    // 0..3
    const int kt_beg = bz * 31;
    const int kt_end = kt_beg + 31;

    // preload this block's (row, slot) offsets
    const int s0 = kt_beg >> 1;
    const int ns = ((kt_end - 1) >> 1) - s0 + 1;   // <= 17
    for (int i = tid; i < ns * 128; i += 256) {
        adr[i >> 7][i & 127] =
            addrs[(size_t)(bm * 128 + (i & 127)) * 64 + s0 + (i >> 7)];
    }

    const int r_l = lane >> 3;                  // staging row within 8-row group
    const int sc16 = ((lane & 7) ^ r_l) * 16;   // XOR-swizzled 16B chunk (bytes)

    const int wn = w & 1;         // n-half: cols wn*64 .. wn*64+63
    const int wk = w >> 1;        // k-slice: elems wk*32 .. wk*32+31 of each BK
    const int n0 = wn * 64;
    const int kk8 = wk * 4 + (lane >> 4);       // global column chunk for frags
    const int fl = lane & 15;

    f32x4 acc[8][4];
#pragma unroll
    for (int i = 0; i < 8; ++i)
#pragma unroll
        for (int j = 0; j < 4; ++j)
#pragma unroll
            for (int r = 0; r < 4; ++r) acc[i][j][r] = 0.f;

    __syncthreads();  // adr visible

    auto stage = [&](int kt, int pb) {
        const int k0 = kt * 64;
        const int sl = (kt >> 1) - s0;
        const int hb = (kt & 1) * 128;
#pragma unroll
        for (int j = 0; j < 4; ++j) {
            const int row = (w * 4 + j) * 8 + r_l;
            const uint8_t* gsrc = wsbase + adr[sl][row] + hb + sc16;
            async16(gsrc, (void*)&As[pb][((w * 4 + j) * 64 + lane) * 8]);
        }
#pragma unroll
        for (int j = 0; j < 4; ++j) {
            const int row = (w * 4 + j) * 8 + r_l;
            const bf16* gsrc = Wcat + (size_t)(bn * 128 + row) * KTOT + k0 + (sc16 >> 1);
            async16(gsrc, (void*)&Bs[pb][((w * 4 + j) * 64 + lane) * 8]);
        }
    };

    stage(kt_beg, 0);   // prologue into buffer 0

    for (int kt = kt_beg; kt < kt_end; ++kt) {
        const int pb = (kt - kt_beg) & 1;
        __syncthreads();
        if (kt + 1 < kt_end) stage(kt + 1, pb ^ 1);

        const bf16* Ab = &As[pb][0];
        const bf16* Bb = &Bs[pb][0];

        bf16x8 bfr[4];
#pragma unroll
        for (int tj = 0; tj < 4; ++tj) {
            const int n = n0 + tj * 16 + fl;
            bfr[tj] = *(const bf16x8*)&Bb[n * 64 + ((kk8 ^ (n & 7)) * 8)];
        }
#pragma unroll
        for (int ti = 0; ti < 8; ++ti) {
            const int m = ti * 16 + fl;
            const bf16x8 af = *(const bf16x8*)&Ab[m * 64 + ((kk8 ^ (m & 7)) * 8)];
#pragma unroll
            for (int tj = 0; tj < 4; ++tj)
                acc[ti][tj] = __builtin_amdgcn_mfma_f32_16x16x32_bf16(
                    af, bfr[tj], acc[ti][tj], 0, 0, 0);
        }
    }

    // ---- reduce wk-partials through LDS (As/Bs are dead now) ----
    __syncthreads();
    float* red = (wn == 0) ? (float*)&As[0][0] : (float*)&Bs[0][0];  // 32 KB each
    if (wk == 1) {
#pragma unroll
        for (int ti = 0; ti < 8; ++ti)
#pragma unroll
            for (int tj = 0; tj < 4; ++tj)
#pragma unroll
                for (int r = 0; r < 4; ++r)
                    red[((ti * 4 + tj) * 4 + r) * 64 + lane] = acc[ti][tj][r];
    }
    __syncthreads();

    if (wk == 0) {
        float* gdst = gpart + (size_t)bz * BATCH * NG;
        const int mlo = (lane >> 4) * 4;
#pragma unroll
        for (int ti = 0; ti < 8; ++ti)
#pragma unroll
            for (int tj = 0; tj < 4; ++tj) {
                const int mg = bm * 128 + ti * 16 + mlo;
                const int ng = bn * 128 + n0 + tj * 16 + fl;
                float* dst = gdst + (size_t)mg * NG + ng;
#pragma unroll
                for (int r = 0; r < 4; ++r)
                    dst[(size_t)r * NG] =
                        acc[ti][tj][r] + red[((ti * 4 + tj) * 4 + r) * 64 + lane];
            }
    }
}

// ---------------------------------------------------------------------------
// Kernel 3: reduce split-K partials + LSTM pointwise.
// 2048 blocks x 256 threads; 2 rows/block, 1 thread per LSTM unit.
// ---------------------------------------------------------------------------
__global__ void reduce_lstm(const float* __restrict__ gpart,
                            const float* __restrict__ bih,
                            const float* __restrict__ bhh,
                            const float* __restrict__ c0,
                            float* __restrict__ out,
                            bf16* __restrict__ h1b) {
    const int t = threadIdx.x;
    const int b = blockIdx.x * 2 + (t >> 7);
    const int u = t & 127;

    float gv[4];
#pragma unroll
    for (int q = 0; q < 4; ++q)
        gv[q] = bih[q * 128 + u] + bhh[q * 128 + u];
#pragma unroll
    for (int z = 0; z < SPLITK; ++z) {
        const float* gz = gpart + ((size_t)z * BATCH + b) * NG + u;
#pragma unroll
        for (int q = 0; q < 4; ++q) gv[q] += gz[q * 128];
    }

    const float iv = 1.f / (1.f + __expf(-gv[0]));
    const float fv = 1.f / (1.f + __expf(-gv[1]));
    const float gg = tanhf(gv[2]);
    const float ov = 1.f / (1.f + __expf(-gv[3]));
    const float c1 = fv * c0[(size_t)b * LH + u] + iv * gg;
    const float h1 = ov * tanhf(c1);

    out[O_H1 + (size_t)b * LH + u] = h1;
    out[O_C1 + (size_t)b * LH + u] = c1;
    h1b[(size_t)b * LH + u] = (bf16)h1;
}

// ---------------------------------------------------------------------------
// Kernel 4: MLP head, 1 wave per block, 16 rows/block, 256 blocks.
// Weight B-fragments read straight global->VGPR from pre-packed L2-resident
// arrays; LDS only for u/feat C->A relayout.
// ---------------------------------------------------------------------------
__global__ __launch_bounds__(64) void mlp_head(
    const bf16* __restrict__ h1b, const float* __restrict__ mask,
    const bf16* __restrict__ W1f, const bf16* __restrict__ W2f,
    const bf16* __restrict__ Waf,
    const float* __restrict__ b1, const float* __restrict__ b2,
    const float* __restrict__ ba,
    float* __restrict__ out) {
    __shared__ bf16 uS[16 * 64];     // 2 KB
    __shared__ bf16 fS[16 * 128];    // 4 KB

    const int lane = threadIdx.x;    // 0..63
    const int b0 = blockIdx.x * 16;
    const int nl = lane & 15, kg = lane >> 4;

    bf16x8 ah[4];
#pragma unroll
    for (int kt = 0; kt < 4; ++kt)
        ah[kt] = *(const bf16x8*)&h1b[(size_t)(b0 + nl) * 128 + kt * 32 + kg * 8];

    // ---- stage 1: u = relu(h1 @ W1^T + b1)  (16x64) ----
#pragma unroll
    for (int nt = 0; nt < 4; ++nt) {
        f32x4 a = {0.f, 0.f, 0.f, 0.f};
#pragma unroll
        for (int kt = 0; kt < 4; ++kt)
            a = __builtin_amdgcn_mfma_f32_16x16x32_bf16(
                ah[kt], *(const bf16x8*)&W1f[((nt * 4 + kt) * 64 + lane) * 8],
                a, 0, 0, 0);
        const int n = nt * 16 + nl;
        const float bb = b1[n];
#pragma unroll
        for (int r = 0; r < 4; ++r)
            uS[(kg * 4 + r) * 64 + n] = (bf16)fmaxf(a[r] + bb, 0.f);
    }
    __syncthreads();

    bf16x8 au[2];
#pragma unroll
    for (int kt = 0; kt < 2; ++kt)
        au[kt] = *(const bf16x8*)&uS[nl * 64 + kt * 32 + kg * 8];

    // ---- stage 2: feat = u @ W2^T + b2  (16x128) ----
#pragma unroll
    for (int nt = 0; nt < 8; ++nt) {
        f32x4 a = {0.f, 0.f, 0.f, 0.f};
#pragma unroll
        for (int kt = 0; kt < 2; ++kt)
            a = __builtin_amdgcn_mfma_f32_16x16x32_bf16(
                au[kt], *(const bf16x8*)&W2f[((nt * 2 + kt) * 64 + lane) * 8],
                a, 0, 0, 0);
        const int n = nt * 16 + nl;
        const float bb = b2[n];
#pragma unroll
        for (int r = 0; r < 4; ++r)
            fS[(kg * 4 + r) * 128 + n] = (bf16)(a[r] + bb);
    }
    __syncthreads();

    bf16x8 afr[4];
#pragma unroll
    for (int kt = 0; kt < 4; ++kt)
        afr[kt] = *(const bf16x8*)&fS[nl * 128 + kt * 32 + kg * 8];

    // ---- stage 3: logits = feat @ Wa^T + ba  (16x16, 9 valid) ----
    f32x4 lg4 = {0.f, 0.f, 0.f, 0.f};
#pragma unroll
    for (int kt = 0; kt < 4; ++kt)
        lg4 = __builtin_amdgcn_mfma_f32_16x16x32_bf16(
            afr[kt], *(const bf16x8*)&Waf[(kt * 64 + lane) * 8], lg4, 0, 0, 0);

    const float bav = (nl < 9) ? ba[nl] : 0.f;

    // ---- softmax + masked renorm; row m = kg*4+r, action = nl ----
#pragma unroll
    for (int r = 0; r < 4; ++r) {
        const int b = b0 + kg * 4 + r;
        float lg = (nl < 9) ? lg4[r] + bav : -1e30f;
        float mx = lg;
#pragma unroll
        for (int off = 1; off < 16; off <<= 1)
            mx = fmaxf(mx, __shfl_xor(mx, off, 64));
        const float e = (nl < 9) ? __expf(lg - mx) : 0.f;
        const float mv = (nl < 9) ? mask[(size_t)b * 9 + nl] : 0.f;
        float tot = e, ms = e * mv;
#pragma unroll
        for (int off = 1; off < 16; off <<= 1) {
            tot += __shfl_xor(tot, off, 64);
            ms += __shfl_xor(ms, off, 64);
        }
        if (nl < 9)
            out[(size_t)b * 9 + nl] = (ms > 0.f) ? e * mv / ms : e / tot;
    }
}

// ---------------------------------------------------------------------------
extern "C" void kernel_launch(void* const* d_in, const int* in_sizes, int n_in,
                              void* d_out, int out_size, void* d_ws, size_t ws_size,
                              hipStream_t stream) {
    const int* ab_ids = (const int*)d_in[0];
    const int* mv_ids = (const int*)d_in[1];
    const float* numerical = (const float*)d_in[2];
    const float* mask = (const float*)d_in[3];
    const float* h0 = (const float*)d_in[4];
    const float* c0 = (const float*)d_in[5];
    const float* ab_emb = (const float*)d_in[6];
    const float* mv_emb = (const float*)d_in[7];
    const float* numW = (const float*)d_in[8];
    const float* numb = (const float*)d_in[9];
    const float* Wih = (const float*)d_in[10];
    const float* Whh = (const float*)d_in[11];
    const float* bih = (const float*)d_in[12];
    const float* bhh = (const float*)d_in[13];
    const float* W1 = (const float*)d_in[14];
    const float* b1 = (const float*)d_in[15];
    const float* W2 = (const float*)d_in[16];
    const float* b2 = (const float*)d_in[17];
    const float* Wa = (const float*)d_in[18];
    const float* ba = (const float*)d_in[19];
    float* out = (float*)d_out;

    uint8_t* ws = (uint8_t*)d_ws;
    bf16* Wcat = (bf16*)(ws + OFF_WCAT);
    float* gpart = (float*)(ws + OFF_GPART);
    uint32_t* addrs = (uint32_t*)(ws + OFF_ADDR);
    bf16* h1b = (bf16*)(ws + OFF_H1B);
    bf16* W1f = (bf16*)(ws + OFF_W1F);
    bf16* W2f = (bf16*)(ws + OFF_W2F);
    bf16* Waf = (bf16*)(ws + OFF_WAF);

    prep<<<BATCH + 512 + 600 + 1, 256, 0, stream>>>(
        ab_ids, mv_ids, numerical, h0, numW, numb, Wih, Whh, ab_emb, mv_emb,
        W1, W2, Wa, ws);
    gemm_gates<<<dim3(32, 4, SPLITK), 256, 0, stream>>>(ws, Wcat, addrs, gpart);
    reduce_lstm<<<BATCH / 2, 256, 0, stream>>>(gpart, bih, bhh, c0, out, h1b);
    mlp_head<<<BATCH / 16, 64, 0, stream>>>(h1b, mask, W1f, W2f, Waf,
                                            b1, b2, ba, out);
}

// Round 13
// 171.447 us; speedup vs baseline: 1.5327x; 1.0560x over previous
//
#include <hip/hip_runtime.h>
#include <hip/hip_bf16.h>
#include <stdint.h>
#include <stddef.h>

typedef __bf16 bf16;
typedef __bf16 bf16x8 __attribute__((ext_vector_type(8)));
typedef float f32x4 __attribute__((ext_vector_type(4)));

#define BATCH 4096
#define KIH 7808          // Wih K
#define KTOT 7936         // 62 slots * 128 (h0 appended)
#define NG 512            // 4*LH gates
#define LH 128
#define HD 64
#define ED 128
#define SPLITK 4

// workspace layout (byte offsets)
#define OFF_WCAT 0u                 //  8,126,464  bf16 Wcat[512][7936]
#define OFF_GPART 8126464u          // 16,777,216  bf16 gpart[4][4096][512]
#define OFF_XT   24903680u          //  2,097,152  bf16 xtail[4096][256]
#define OFF_AB   27000832u          //     76,800  bf16 ab8[300][128]
#define OFF_MV   27077632u          //    230,400  bf16 mv8[900][128]
#define OFF_ADDR 27308032u          //  1,048,576  u32 addrs[4096][64]
#define OFF_H1B  28356608u          //  1,048,576  bf16 h1b[4096][128]
#define OFF_W1F  29405184u          //     16,384  bf16 W1 fragments
#define OFF_W2F  29421568u          //     16,384  bf16 W2 fragments
#define OFF_WAF  29437952u          //      4,096  bf16 Wa fragments
#define OFF_NB   29442048u          //      2,048  f32 nbias[512]
// end: 29,444,096 B

// out layout: probs[B*9] | h1[B*128] | c1[B*128]
#define O_H1 (BATCH * 9)
#define O_C1 (BATCH * 9 + BATCH * LH)

// ---------------------------------------------------------------------------
typedef const __attribute__((address_space(1))) uint32_t* gas_ptr;
typedef __attribute__((address_space(3))) uint32_t* las_ptr;

__device__ __forceinline__ void async16(const void* g, void* l) {
    __builtin_amdgcn_global_load_lds((gas_ptr)g, (las_ptr)l, 16, 0, 0);
}

// ---------------------------------------------------------------------------
// Kernel 1: fused prep.
//   blocks 0..4095:      build_pre (per-row offsets + xtail = [num_pad|h0])
//   blocks 4096..4607:   convert_w + numproj weight folding + nbias
//   blocks 4608..5207:   convert_emb
//   block  5208:         pack MLP weight fragments
// ---------------------------------------------------------------------------
__global__ void prep(const int* __restrict__ ab_ids,
                     const int* __restrict__ mv_ids,
                     const float* __restrict__ numerical,
                     const float* __restrict__ h0,
                     const float* __restrict__ numW,
                     const float* __restrict__ numb,
                     const float* __restrict__ Wih,
                     const float* __restrict__ Whh,
                     const float* __restrict__ ab_emb,
                     const float* __restrict__ mv_emb,
                     const float* __restrict__ W1,
                     const float* __restrict__ W2,
                     const float* __restrict__ Wa,
                     uint8_t* __restrict__ ws) {
    const int bid = blockIdx.x;
    const int t = threadIdx.x;  // 0..255

    if (bid < BATCH) {
        // ---- build_pre: xtail + gather offsets (no matvec any more) ----
        bf16* xtail = (bf16*)(ws + OFF_XT);
        uint32_t* addrs = (uint32_t*)(ws + OFF_ADDR);
        const int b = bid;

        __shared__ int ids[60];
        if (t < 60) ids[t] = (t < 12) ? ab_ids[b * 12 + t] : mv_ids[b * 48 + (t - 12)];

        if (t < 128) {
            const float v = (t < 84) ? numerical[(size_t)b * 84 + t] : 0.f;
            xtail[(size_t)b * 256 + t] = (bf16)v;
        } else {
            const int tt = t - 128;
            xtail[(size_t)b * 256 + 128 + tt] = (bf16)h0[(size_t)b * LH + tt];
        }
        __syncthreads();

        if (t < 64) {
            uint32_t off;
            if (t < 12) off = OFF_AB + (uint32_t)ids[t] * 256u;
            else if (t < 60) off = OFF_MV + (uint32_t)ids[t] * 256u;
            else if (t == 60) off = OFF_XT + (uint32_t)b * 512u;
            else if (t == 61) off = OFF_XT + (uint32_t)b * 512u + 256u;
            else off = OFF_XT;  // unused slots 62,63
            addrs[(size_t)b * 64 + t] = off;
        }
    } else if (bid < BATCH + 512) {
        // ---- convert_w: cols [0,7680) direct; slot 60 = Wfold; then Whh ----
        bf16* Wcat = (bf16*)(ws + OFF_WCAT);
        float* nbias = (float*)(ws + OFF_NB);
        const int n = bid - BATCH;

        __shared__ float wrow[128];   // Wih[n][7680..7808)
        __shared__ float nbs[128];
        if (t < 128) wrow[t] = Wih[(size_t)n * KIH + 7680 + t];
        else nbs[t - 128] = numb[t - 128];
        __syncthreads();

        const float* src_ih = Wih + (size_t)n * KIH;
        bf16* dst = Wcat + (size_t)n * KTOT;
        for (int k4 = t; k4 < 1920; k4 += 256) {   // 7680/4
            const int k = k4 * 4;
            const float4 v = *(const float4*)(src_ih + k);
            bf16 o0 = (bf16)v.x, o1 = (bf16)v.y, o2 = (bf16)v.z, o3 = (bf16)v.w;
            dst[k] = o0; dst[k + 1] = o1; dst[k + 2] = o2; dst[k + 3] = o3;
        }
        if (t < 84) {
            // Wfold[n][t] = sum_e Wih[n][7680+e] * numW[e][t]
            float acc = 0.f;
#pragma unroll 4
            for (int e = 0; e < 128; ++e)
                acc += wrow[e] * numW[e * 84 + t];
            dst[7680 + t] = (bf16)acc;
        } else if (t < 128) {
            dst[7680 + t] = (bf16)0.f;     // padding cols (x is zero there too)
        } else {
            const int tt = t - 128;
            dst[KIH + tt] = (bf16)Whh[(size_t)n * LH + tt];
        }
        if (t == 255) {
            float a = 0.f;
#pragma unroll 4
            for (int e = 0; e < 128; ++e) a += wrow[e] * nbs[e];
            nbias[n] = a;
        }
    } else if (bid < BATCH + 512 + 600) {
        // ---- convert_emb ----
        bf16* ab8 = (bf16*)(ws + OFF_AB);
        bf16* mv8 = (bf16*)(ws + OFF_MV);
        const int i = (bid - BATCH - 512) * 256 + t;   // 0..153599
        if (i < 300 * 128) ab8[i] = (bf16)ab_emb[i];
        else if (i < 1200 * 128) mv8[i - 300 * 128] = (bf16)mv_emb[i - 300 * 128];
    } else {
        // ---- pack MLP weight fragments (B-frag: lane n=l&15, k=(l>>4)*8+j) --
        bf16* W1f = (bf16*)(ws + OFF_W1F);
        bf16* W2f = (bf16*)(ws + OFF_W2F);
        bf16* Waf = (bf16*)(ws + OFF_WAF);
        for (int e = t; e < 8192; e += 256) {     // W1 (64x128), fid = nt*4+kt
            const int j = e & 7, ln = (e >> 3) & 63, fid = e >> 9;
            const int kt = fid & 3, nt = fid >> 2;
            const int n = nt * 16 + (ln & 15);
            const int k = kt * 32 + (ln >> 4) * 8 + j;
            W1f[e] = (bf16)W1[n * 128 + k];
        }
        for (int e = t; e < 8192; e += 256) {     // W2 (128x64), fid = nt*2+kt
            const int j = e & 7, ln = (e >> 3) & 63, fid = e >> 9;
            const int kt = fid & 1, nt = fid >> 1;
            const int n = nt * 16 + (ln & 15);
            const int k = kt * 32 + (ln >> 4) * 8 + j;
            W2f[e] = (bf16)W2[n * 64 + k];
        }
        for (int e = t; e < 2048; e += 256) {     // Wa (9x128 zero-padded)
            const int j = e & 7, ln = (e >> 3) & 63, kt = e >> 9;
            const int n = ln & 15;
            const int k = kt * 32 + (ln >> 4) * 8 + j;
            Waf[e] = (n < 9) ? (bf16)Wa[n * 128 + k] : (bf16)0.f;
        }
    }
}

// ---------------------------------------------------------------------------
// Kernel 2: gpart[bz] = x @ Wcat.T partial  (x gathered on the fly)
// 128x128 block tile, BK=64, XOR-swizzled LDS, double-buffered, split-K=4.
// Intra-block K-split: 4 waves = 2 n-halves x 2 k-slices; wk-partials
// reduced through LDS.  Partials stored bf16 (plain stores).
// ---------------------------------------------------------------------------
__global__ __launch_bounds__(256, 2) void gemm_gates(
    const uint8_t* __restrict__ wsbase,
    const bf16* __restrict__ Wcat,
    const uint32_t* __restrict__ addrs,
    bf16* __restrict__ gpart) {
    __shared__ bf16 As[2][128 * 64];    // 2 x 16 KB
    __shared__ bf16 Bs[2][128 * 64];    // 2 x 16 KB
    __shared__ uint32_t adr[17][128];   // 8.5 KB

    const int tid = threadIdx.x;
    const int w = tid >> 6;       // wave 0..3
    const int lane = tid & 63;
    const int bm = blockIdx.x;    // 0..31
    const int bn = blockIdx.y;    // 0..3
    const int bz = blockIdx.z;    // 0..3
    const int kt_beg = bz * 31;
    const int kt_end = kt_beg + 31;

    // preload this block's (row, slot) offsets
    const int s0 = kt_beg >> 1;
    const int ns = ((kt_end - 1) >> 1) - s0 + 1;   // <= 17
    for (int i = tid; i < ns * 128; i += 256) {
        adr[i >> 7][i & 127] =
            addrs[(size_t)(bm * 128 + (i & 127)) * 64 + s0 + (i >> 7)];
    }

    const int r_l = lane >> 3;                  // staging row within 8-row group
    const int sc16 = ((lane & 7) ^ r_l) * 16;   // XOR-swizzled 16B chunk (bytes)

    const int wn = w & 1;         // n-half: cols wn*64 .. wn*64+63
    const int wk = w >> 1;        // k-slice: elems wk*32 .. wk*32+31 of each BK
    const int n0 = wn * 64;
    const int kk8 = wk * 4 + (lane >> 4);       // global column chunk for frags
    const int fl = lane & 15;

    f32x4 acc[8][4];
#pragma unroll
    for (int i = 0; i < 8; ++i)
#pragma unroll
        for (int j = 0; j < 4; ++j)
#pragma unroll
            for (int r = 0; r < 4; ++r) acc[i][j][r] = 0.f;

    __syncthreads();  // adr visible

    auto stage = [&](int kt, int pb) {
        const int k0 = kt * 64;
        const int sl = (kt >> 1) - s0;
        const int hb = (kt & 1) * 128;
#pragma unroll
        for (int j = 0; j < 4; ++j) {
            const int row = (w * 4 + j) * 8 + r_l;
            const uint8_t* gsrc = wsbase + adr[sl][row] + hb + sc16;
            async16(gsrc, (void*)&As[pb][((w * 4 + j) * 64 + lane) * 8]);
        }
#pragma unroll
        for (int j = 0; j < 4; ++j) {
            const int row = (w * 4 + j) * 8 + r_l;
            const bf16* gsrc = Wcat + (size_t)(bn * 128 + row) * KTOT + k0 + (sc16 >> 1);
            async16(gsrc, (void*)&Bs[pb][((w * 4 + j) * 64 + lane) * 8]);
        }
    };

    stage(kt_beg, 0);   // prologue into buffer 0

    for (int kt = kt_beg; kt < kt_end; ++kt) {
        const int pb = (kt - kt_beg) & 1;
        __syncthreads();
        if (kt + 1 < kt_end) stage(kt + 1, pb ^ 1);

        const bf16* Ab = &As[pb][0];
        const bf16* Bb = &Bs[pb][0];

        bf16x8 bfr[4];
#pragma unroll
        for (int tj = 0; tj < 4; ++tj) {
            const int n = n0 + tj * 16 + fl;
            bfr[tj] = *(const bf16x8*)&Bb[n * 64 + ((kk8 ^ (n & 7)) * 8)];
        }
#pragma unroll
        for (int ti = 0; ti < 8; ++ti) {
            const int m = ti * 16 + fl;
            const bf16x8 af = *(const bf16x8*)&Ab[m * 64 + ((kk8 ^ (m & 7)) * 8)];
#pragma unroll
            for (int tj = 0; tj < 4; ++tj)
                acc[ti][tj] = __builtin_amdgcn_mfma_f32_16x16x32_bf16(
                    af, bfr[tj], acc[ti][tj], 0, 0, 0);
        }
    }

    // ---- reduce wk-partials through LDS (As/Bs are dead now) ----
    __syncthreads();
    float* red = (wn == 0) ? (float*)&As[0][0] : (float*)&Bs[0][0];  // 32 KB each
    if (wk == 1) {
#pragma unroll
        for (int ti = 0; ti < 8; ++ti)
#pragma unroll
            for (int tj = 0; tj < 4; ++tj)
#pragma unroll
                for (int r = 0; r < 4; ++r)
                    red[((ti * 4 + tj) * 4 + r) * 64 + lane] = acc[ti][tj][r];
    }
    __syncthreads();

    if (wk == 0) {
        bf16* gdst = gpart + (size_t)bz * BATCH * NG;
        const int mlo = (lane >> 4) * 4;
#pragma unroll
        for (int ti = 0; ti < 8; ++ti)
#pragma unroll
            for (int tj = 0; tj < 4; ++tj) {
                const int mg = bm * 128 + ti * 16 + mlo;
                const int ng = bn * 128 + n0 + tj * 16 + fl;
                bf16* dst = gdst + (size_t)mg * NG + ng;
#pragma unroll
                for (int r = 0; r < 4; ++r)
                    dst[(size_t)r * NG] = (bf16)(
                        acc[ti][tj][r] + red[((ti * 4 + tj) * 4 + r) * 64 + lane]);
            }
    }
}

// ---------------------------------------------------------------------------
// Kernel 3: reduce split-K partials + LSTM pointwise.
// 2048 blocks x 256 threads; 2 rows/block, 1 thread per LSTM unit.
// ---------------------------------------------------------------------------
__global__ void reduce_lstm(const bf16* __restrict__ gpart,
                            const float* __restrict__ bih,
                            const float* __restrict__ bhh,
                            const float* __restrict__ nbias,
                            const float* __restrict__ c0,
                            float* __restrict__ out,
                            bf16* __restrict__ h1b) {
    const int t = threadIdx.x;
    const int b = blockIdx.x * 2 + (t >> 7);
    const int u = t & 127;

    float gv[4];
#pragma unroll
    for (int q = 0; q < 4; ++q)
        gv[q] = bih[q * 128 + u] + bhh[q * 128 + u] + nbias[q * 128 + u];
#pragma unroll
    for (int z = 0; z < SPLITK; ++z) {
        const bf16* gz = gpart + ((size_t)z * BATCH + b) * NG + u;
#pragma unroll
        for (int q = 0; q < 4; ++q) gv[q] += (float)gz[q * 128];
    }

    const float iv = 1.f / (1.f + __expf(-gv[0]));
    const float fv = 1.f / (1.f + __expf(-gv[1]));
    const float gg = tanhf(gv[2]);
    const float ov = 1.f / (1.f + __expf(-gv[3]));
    const float c1 = fv * c0[(size_t)b * LH + u] + iv * gg;
    const float h1 = ov * tanhf(c1);

    out[O_H1 + (size_t)b * LH + u] = h1;
    out[O_C1 + (size_t)b * LH + u] = c1;
    h1b[(size_t)b * LH + u] = (bf16)h1;
}

// ---------------------------------------------------------------------------
// Kernel 4: MLP head, 1 wave per block, 16 rows/block, 256 blocks.
// Weight B-fragments read straight global->VGPR from pre-packed L2-resident
// arrays; LDS only for u/feat C->A relayout.
// ---------------------------------------------------------------------------
__global__ __launch_bounds__(64) void mlp_head(
    const bf16* __restrict__ h1b, const float* __restrict__ mask,
    const bf16* __restrict__ W1f, const bf16* __restrict__ W2f,
    const bf16* __restrict__ Waf,
    const float* __restrict__ b1, const float* __restrict__ b2,
    const float* __restrict__ ba,
    float* __restrict__ out) {
    __shared__ bf16 uS[16 * 64];     // 2 KB
    __shared__ bf16 fS[16 * 128];    // 4 KB

    const int lane = threadIdx.x;    // 0..63
    const int b0 = blockIdx.x * 16;
    const int nl = lane & 15, kg = lane >> 4;

    bf16x8 ah[4];
#pragma unroll
    for (int kt = 0; kt < 4; ++kt)
        ah[kt] = *(const bf16x8*)&h1b[(size_t)(b0 + nl) * 128 + kt * 32 + kg * 8];

    // ---- stage 1: u = relu(h1 @ W1^T + b1)  (16x64) ----
#pragma unroll
    for (int nt = 0; nt < 4; ++nt) {
        f32x4 a = {0.f, 0.f, 0.f, 0.f};
#pragma unroll
        for (int kt = 0; kt < 4; ++kt)
            a = __builtin_amdgcn_mfma_f32_16x16x32_bf16(
                ah[kt], *(const bf16x8*)&W1f[((nt * 4 + kt) * 64 + lane) * 8],
                a, 0, 0, 0);
        const int n = nt * 16 + nl;
        const float bb = b1[n];
#pragma unroll
        for (int r = 0; r < 4; ++r)
            uS[(kg * 4 + r) * 64 + n] = (bf16)fmaxf(a[r] + bb, 0.f);
    }
    __syncthreads();

    bf16x8 au[2];
#pragma unroll
    for (int kt = 0; kt < 2; ++kt)
        au[kt] = *(const bf16x8*)&uS[nl * 64 + kt * 32 + kg * 8];

    // ---- stage 2: feat = u @ W2^T + b2  (16x128) ----
#pragma unroll
    for (int nt = 0; nt < 8; ++nt) {
        f32x4 a = {0.f, 0.f, 0.f, 0.f};
#pragma unroll
        for (int kt = 0; kt < 2; ++kt)
            a = __builtin_amdgcn_mfma_f32_16x16x32_bf16(
                au[kt], *(const bf16x8*)&W2f[((nt * 2 + kt) * 64 + lane) * 8],
                a, 0, 0, 0);
        const int n = nt * 16 + nl;
        const float bb = b2[n];
#pragma unroll
        for (int r = 0; r < 4; ++r)
            fS[(kg * 4 + r) * 128 + n] = (bf16)(a[r] + bb);
    }
    __syncthreads();

    bf16x8 afr[4];
#pragma unroll
    for (int kt = 0; kt < 4; ++kt)
        afr[kt] = *(const bf16x8*)&fS[nl * 128 + kt * 32 + kg * 8];

    // ---- stage 3: logits = feat @ Wa^T + ba  (16x16, 9 valid) ----
    f32x4 lg4 = {0.f, 0.f, 0.f, 0.f};
#pragma unroll
    for (int kt = 0; kt < 4; ++kt)
        lg4 = __builtin_amdgcn_mfma_f32_16x16x32_bf16(
            afr[kt], *(const bf16x8*)&Waf[(kt * 64 + lane) * 8], lg4, 0, 0, 0);

    const float bav = (nl < 9) ? ba[nl] : 0.f;

    // ---- softmax + masked renorm; row m = kg*4+r, action = nl ----
#pragma unroll
    for (int r = 0; r < 4; ++r) {
        const int b = b0 + kg * 4 + r;
        float lg = (nl < 9) ? lg4[r] + bav : -1e30f;
        float mx = lg;
#pragma unroll
        for (int off = 1; off < 16; off <<= 1)
            mx = fmaxf(mx, __shfl_xor(mx, off, 64));
        const float e = (nl < 9) ? __expf(lg - mx) : 0.f;
        const float mv = (nl < 9) ? mask[(size_t)b * 9 + nl] : 0.f;
        float tot = e, ms = e * mv;
#pragma unroll
        for (int off = 1; off < 16; off <<= 1) {
            tot += __shfl_xor(tot, off, 64);
            ms += __shfl_xor(ms, off, 64);
        }
        if (nl < 9)
            out[(size_t)b * 9 + nl] = (ms > 0.f) ? e * mv / ms : e / tot;
    }
}

// ---------------------------------------------------------------------------
extern "C" void kernel_launch(void* const* d_in, const int* in_sizes, int n_in,
                              void* d_out, int out_size, void* d_ws, size_t ws_size,
                              hipStream_t stream) {
    const int* ab_ids = (const int*)d_in[0];
    const int* mv_ids = (const int*)d_in[1];
    const float* numerical = (const float*)d_in[2];
    const float* mask = (const float*)d_in[3];
    const float* h0 = (const float*)d_in[4];
    const float* c0 = (const float*)d_in[5];
    const float* ab_emb = (const float*)d_in[6];
    const float* mv_emb = (const float*)d_in[7];
    const float* numW = (const float*)d_in[8];
    const float* numb = (const float*)d_in[9];
    const float* Wih = (const float*)d_in[10];
    const float* Whh = (const float*)d_in[11];
    const float* bih = (const float*)d_in[12];
    const float* bhh = (const float*)d_in[13];
    const float* W1 = (const float*)d_in[14];
    const float* b1 = (const float*)d_in[15];
    const float* W2 = (const float*)d_in[16];
    const float* b2 = (const float*)d_in[17];
    const float* Wa = (const float*)d_in[18];
    const float* ba = (const float*)d_in[19];
    float* out = (float*)d_out;

    uint8_t* ws = (uint8_t*)d_ws;
    bf16* Wcat = (bf16*)(ws + OFF_WCAT);
    bf16* gpart = (bf16*)(ws + OFF_GPART);
    uint32_t* addrs = (uint32_t*)(ws + OFF_ADDR);
    bf16* h1b = (bf16*)(ws + OFF_H1B);
    bf16* W1f = (bf16*)(ws + OFF_W1F);
    bf16* W2f = (bf16*)(ws + OFF_W2F);
    bf16* Waf = (bf16*)(ws + OFF_WAF);
    float* nbias = (float*)(ws + OFF_NB);

    prep<<<BATCH + 512 + 600 + 1, 256, 0, stream>>>(
        ab_ids, mv_ids, numerical, h0, numW, numb, Wih, Whh, ab_emb, mv_emb,
        W1, W2, Wa, ws);
    gemm_gates<<<dim3(32, 4, SPLITK), 256, 0, stream>>>(ws, Wcat, addrs, gpart);
    reduce_lstm<<<BATCH / 2, 256, 0, stream>>>(gpart, bih, bhh, nbias, c0,
                                               out, h1b);
    mlp_head<<<BATCH / 16, 64, 0, stream>>>(h1b, mask, W1f, W2f, Waf,
                                            b1, b2, ba, out);
}